// Round 6
// baseline (482.242 us; speedup 1.0000x reference)
//
#include <hip/hip_runtime.h>
#include <hip/hip_bf16.h>
#include <math.h>

// Round 5: attn_pv uses operand-swapped QK^T so the P-tile exits MFMA with
// 4 consecutive s per lane -> packed cvt + ds_write_b64 (kills the VALU-bound
// f2bf/b16-store epilogue). V^T fold+transpose merged into attn_colsum.
// GEMM unchanged from R4 (XCD swizzle + BK=64).

using bf16x8 = __attribute__((ext_vector_type(8))) short;
using f32x4  = __attribute__((ext_vector_type(4))) float;

__device__ inline f32x4 mfma16(bf16x8 a, bf16x8 b, f32x4 c) {
    return __builtin_amdgcn_mfma_f32_16x16x32_bf16(a, b, c, 0, 0, 0);
}

__device__ inline ushort f2bf(float f) {
    union { float f; unsigned u; } x; x.f = f;
    unsigned r = x.u + 0x7fffu + ((x.u >> 16) & 1u);
    return (ushort)(r >> 16);
}

__device__ inline float bf2f(ushort u) {
    union { unsigned u; float f; } x; x.u = ((unsigned)u) << 16; return x.f;
}

// pack two floats -> two bf16 (v_cvt_pk_bf16_f32 on gfx950)
__device__ inline unsigned pk2bf(float a, float b) {
    __hip_bfloat162 h = __float22bfloat162_rn(float2{a, b});
    union { __hip_bfloat162 h; unsigned u; } x; x.h = h;
    return x.u;
}

// tanh-form gelu: v * sigmoid(1.59577v + 0.071355v^3); max |err| vs erf ~3e-3
__device__ inline float gelu_fast(float v) {
    float u = v * (1.5957691216f + 0.0713548162f * v * v);
    float e = __expf(u);
    return v * (e / (e + 1.0f));
}

// async 16B global -> LDS (wave-uniform LDS base + lane*16)
__device__ __forceinline__ void gl2lds16(const ushort* g, ushort* l) {
    __builtin_amdgcn_global_load_lds(
        (const __attribute__((address_space(1))) unsigned int*)g,
        (__attribute__((address_space(3))) unsigned int*)l,
        16, 0, 0);
}

// ---------------- merged fp32 -> bf16 convert ----------------
__global__ __launch_bounds__(256) void cvt_all(const float4* __restrict__ s0,
                                               const float4* __restrict__ s1,
                                               const float4* __restrict__ s2,
                                               const float4* __restrict__ s3,
                                               const float4* __restrict__ s4,
                                               ushort4* __restrict__ out) {
    int i = blockIdx.x * 256 + threadIdx.x;
    const float4* p;
    int off;
    if (i < 1048576)      { p = s0; off = i; }
    else if (i < 1835008) { p = s1; off = i - 1048576; }
    else if (i < 2097152) { p = s2; off = i - 1835008; }
    else if (i < 3145728) { p = s3; off = i - 2097152; }
    else                  { p = s4; off = i - 3145728; }
    float4 v = p[off];
    ushort4 o;
    o.x = f2bf(v.x); o.y = f2bf(v.y); o.z = f2bf(v.z); o.w = f2bf(v.w);
    out[i] = o;
}

// ---------------- GEMM: out[M,N] = A[M,K] @ Bw[N,K]^T (+ bias) ----------------
// mode 0: QKV epilogue -> ob0 (Q), ob1 (K), ob2 (V row-major); +bias
// mode 2: bf16 out = gelu(acc + bias)
// mode 3: bf16 partial: ob0[z*M*N + idx] = acc (bias added in LN combine)
__global__ __launch_bounds__(256) void gemm_bt(
    const ushort* __restrict__ A, const ushort* __restrict__ Bw,
    const float* __restrict__ bias, int M, int N, int K, int kLen, int mode,
    ushort* __restrict__ ob0, ushort* __restrict__ ob1, ushort* __restrict__ ob2) {
    __shared__ ushort As[2][128 * 32];
    __shared__ ushort Bs[2][128 * 32];
    int tid = threadIdx.x, lane = tid & 63, w = tid >> 6;
    int wm = w >> 1, wn = w & 1;

    // XCD-aware swizzle: slab c = i%8 covers y-band [c*Ny/8, (c+1)*Ny/8)
    int Nx = gridDim.x, Ny = gridDim.y;
    int bx = blockIdx.x, by = blockIdx.y;
    if ((Ny & 7) == 0) {
        int i = bx + Nx * by;
        int c = i & 7, j = i >> 3;
        bx = j % Nx;
        by = c * (Ny >> 3) + j / Nx;
    }
    int bm = by * 128, bn = bx * 128;
    int kz = blockIdx.z;
    int q4 = lane >> 4, l15 = lane & 15;
    f32x4 acc[4][4] = {};

    int srow = w * 16 + (lane >> 2);
    int scg = lane & 3;
    const ushort* Ab = A + (size_t)bm * K + (size_t)kz * kLen;
    const ushort* Bb = Bw + (size_t)bn * K + (size_t)kz * kLen;
    const ushort* gA0 = Ab + (size_t)srow * K + scg * 8;
    const ushort* gA1 = Ab + (size_t)(64 + srow) * K + scg * 8;
    const ushort* gB0 = Bb + (size_t)srow * K + scg * 8;
    const ushort* gB1 = Bb + (size_t)(64 + srow) * K + scg * 8;
    ushort* lA00 = As[0] + w * 512;
    ushort* lA10 = As[0] + 2048 + w * 512;
    ushort* lB00 = Bs[0] + w * 512;
    ushort* lB10 = Bs[0] + 2048 + w * 512;
    ushort* lA01 = As[1] + w * 512;
    ushort* lA11 = As[1] + 2048 + w * 512;
    ushort* lB01 = Bs[1] + w * 512;
    ushort* lB11 = Bs[1] + 2048 + w * 512;

    const ushort* aB[2] = { &As[0][(wm * 64 + l15) * 32 + q4 * 8],
                            &As[1][(wm * 64 + l15) * 32 + q4 * 8] };
    const ushort* bB[2] = { &Bs[0][(wn * 64 + l15) * 32 + q4 * 8],
                            &Bs[1][(wn * 64 + l15) * 32 + q4 * 8] };

    for (int k0 = 0; k0 < kLen; k0 += 64) {
        __syncthreads();
        gl2lds16(gA0 + k0, lA00);
        gl2lds16(gA1 + k0, lA10);
        gl2lds16(gB0 + k0, lB00);
        gl2lds16(gB1 + k0, lB10);
        gl2lds16(gA0 + k0 + 32, lA01);
        gl2lds16(gA1 + k0 + 32, lA11);
        gl2lds16(gB0 + k0 + 32, lB01);
        gl2lds16(gB1 + k0 + 32, lB11);
        __syncthreads();
#pragma unroll
        for (int u = 0; u < 2; u++) {
            bf16x8 af[4], bfr[4];
#pragma unroll
            for (int mi = 0; mi < 4; mi++)
                af[mi] = *(const bf16x8*)(aB[u] + mi * 512);
#pragma unroll
            for (int ni = 0; ni < 4; ni++)
                bfr[ni] = *(const bf16x8*)(bB[u] + ni * 512);
#pragma unroll
            for (int mi = 0; mi < 4; mi++)
#pragma unroll
                for (int ni = 0; ni < 4; ni++)
                    acc[mi][ni] = mfma16(af[mi], bfr[ni], acc[mi][ni]);
        }
    }

    int r0 = bm + wm * 64, c0 = bn + wn * 64;
#pragma unroll
    for (int mi = 0; mi < 4; mi++) {
#pragma unroll
        for (int ni = 0; ni < 4; ni++) {
            int colg = c0 + ni * 16 + l15;
            float bv = (mode == 3) ? 0.f : bias[colg];
#pragma unroll
            for (int r = 0; r < 4; r++) {
                int rowg = r0 + mi * 16 + q4 * 4 + r;
                float v = acc[mi][ni][r] + bv;
                if (mode == 0) {
                    if (colg < 1024) {
                        ob0[(size_t)rowg * 1024 + colg] = f2bf(v);
                    } else if (colg < 2048) {
                        ob1[(size_t)rowg * 1024 + (colg - 1024)] = f2bf(v);
                    } else {
                        ob2[(size_t)rowg * 1024 + (colg - 2048)] = f2bf(v);
                    }
                } else if (mode == 2) {
                    ob0[(size_t)rowg * N + colg] = f2bf(gelu_fast(v));
                } else {
                    ob0[(size_t)kz * M * N + (size_t)rowg * N + colg] = f2bf(v);
                }
            }
        }
    }
}

// ---------------- attention pass A + V fold/transpose ----------------
// Block = (bh, 128-s chunk). Computes ninv[s] = 1/sum_t exp(q.k/8) for its
// 128 s, then writes vt[bh][dh][s] = vrow[s][dh] * ninv[s].
__global__ __launch_bounds__(256) void attn_colsum_foldv(const ushort* __restrict__ qb,
                                                         const ushort* __restrict__ kb,
                                                         const ushort* __restrict__ vrow,
                                                         ushort* __restrict__ vt) {
    __shared__ ushort Qs[64 * 72];
    __shared__ float NinvS[128];
    int tid = threadIdx.x, lane = tid & 63, w = tid >> 6;
    int bh = blockIdx.x >> 4, sblk = blockIdx.x & 15;
    int b = bh >> 4, h = bh & 15;
    int q4 = lane >> 4, l15 = lane & 15;
    const ushort* qbase = qb + (size_t)(b * 2048) * 1024 + h * 64;
    const ushort* kbase = kb + (size_t)(b * 2048) * 1024 + h * 64;
    int s_base = sblk * 128 + w * 32;

    bf16x8 ka[2][2];
#pragma unroll
    for (int mi = 0; mi < 2; mi++) {
        const ushort* kp = kbase + (size_t)(s_base + mi * 16 + l15) * 1024 + q4 * 8;
        ka[mi][0] = *(const bf16x8*)(kp);
        ka[mi][1] = *(const bf16x8*)(kp + 32);
    }
    float acc[2][4] = {};

    int sr = tid >> 3;
    int sc = (tid & 7) * 8;
    for (int t0 = 0; t0 < 2048; t0 += 64) {
        uint4 g0 = *(const uint4*)(qbase + (size_t)(t0 + sr) * 1024 + sc);
        uint4 g1 = *(const uint4*)(qbase + (size_t)(t0 + 32 + sr) * 1024 + sc);
        __syncthreads();
        *(uint4*)&Qs[sr * 72 + sc] = g0;
        *(uint4*)&Qs[(32 + sr) * 72 + sc] = g1;
        __syncthreads();
#pragma unroll
        for (int tsub = 0; tsub < 4; tsub++) {
            bf16x8 bq0 = *(const bf16x8*)&Qs[(tsub * 16 + l15) * 72 + q4 * 8];
            bf16x8 bq1 = *(const bf16x8*)&Qs[(tsub * 16 + l15) * 72 + 32 + q4 * 8];
#pragma unroll
            for (int mi = 0; mi < 2; mi++) {
                f32x4 d = {0.f, 0.f, 0.f, 0.f};
                d = mfma16(ka[mi][0], bq0, d);
                d = mfma16(ka[mi][1], bq1, d);
#pragma unroll
                for (int r = 0; r < 4; r++)
                    acc[mi][r] += __expf(d[r] * 0.125f);
            }
        }
    }
#pragma unroll
    for (int mi = 0; mi < 2; mi++)
#pragma unroll
        for (int r = 0; r < 4; r++) {
            float v = acc[mi][r];
            v += __shfl_xor(v, 1); v += __shfl_xor(v, 2);
            v += __shfl_xor(v, 4); v += __shfl_xor(v, 8);
            if (l15 == 0)
                NinvS[w * 32 + mi * 16 + q4 * 4 + r] = 1.f / v;
        }

    // ---- fold ninv into V and transpose to vt[bh][dh][s] (two 64-s batches) ----
    int sl = tid >> 3, dh8 = (tid & 7) * 8;
#pragma unroll
    for (int batch = 0; batch < 2; batch++) {
        int bs = sblk * 128 + batch * 64;
        __syncthreads();          // Qs free / previous batch's reads done
#pragma unroll
        for (int rep = 0; rep < 2; rep++) {
            int s = sl + rep * 32;
            float n = NinvS[batch * 64 + s];
            const ushort* p = vrow + (size_t)(b * 2048 + bs + s) * 1024 + h * 64 + dh8;
            ushort4 u0 = ((const ushort4*)p)[0];
            ushort4 u1 = ((const ushort4*)p)[1];
            ushort4 o0, o1;
            o0.x = f2bf(bf2f(u0.x) * n); o0.y = f2bf(bf2f(u0.y) * n);
            o0.z = f2bf(bf2f(u0.z) * n); o0.w = f2bf(bf2f(u0.w) * n);
            o1.x = f2bf(bf2f(u1.x) * n); o1.y = f2bf(bf2f(u1.y) * n);
            o1.z = f2bf(bf2f(u1.z) * n); o1.w = f2bf(bf2f(u1.w) * n);
            *(ushort4*)&Qs[s * 72 + dh8] = o0;
            *(ushort4*)&Qs[s * 72 + dh8 + 4] = o1;
        }
        __syncthreads();
        int dhl = tid >> 3, soff = (tid & 7) * 8;
#pragma unroll
        for (int rep = 0; rep < 2; rep++) {
            int d = dhl + rep * 32;
            ushort tmp[8];
#pragma unroll
            for (int j = 0; j < 8; j++) tmp[j] = Qs[(soff + j) * 72 + d];
            *(uint4*)(vt + ((size_t)bh * 64 + d) * 2048 + bs + soff) = *(uint4*)tmp;
        }
    }
}

// ---------------- attention pass B: post = gelu(exp(QK/8) @ Vscaled)/sqrt(S) ----------------
// Operand-swapped QK^T: C gives lane (q4,l15) -> t=l15, s=q4*4+r (4 consecutive s)
// => packed cvt + ds_write_b64 straight into PV-A-operand layout Pt[t][s].
__global__ __launch_bounds__(256) void attn_pv(const ushort* __restrict__ qb,
                                               const ushort* __restrict__ kb,
                                               const ushort* __restrict__ vt,
                                               ushort* __restrict__ post) {
    __shared__ ushort Ks[64 * 72];
    __shared__ ushort Vs[64 * 72];
    __shared__ ushort Ps[4][32 * 68];       // per-wave Pt[t 0..31][s 0..63], stride 68
    int tid = threadIdx.x, lane = tid & 63, w = tid >> 6;
    int bh = blockIdx.x >> 4, tblk = blockIdx.x & 15;
    int b = bh >> 4, h = bh & 15;
    int q4 = lane >> 4, l15 = lane & 15;
    const ushort* qbase = qb + (size_t)(b * 2048) * 1024 + h * 64;
    const ushort* kbase = kb + (size_t)(b * 2048) * 1024 + h * 64;
    const ushort* vtb = vt + (size_t)bh * 64 * 2048;
    int t_base = tblk * 128 + w * 32;

    bf16x8 aq[2][2];
#pragma unroll
    for (int mi = 0; mi < 2; mi++) {
        const ushort* qp = qbase + (size_t)(t_base + mi * 16 + l15) * 1024 + q4 * 8;
        aq[mi][0] = *(const bf16x8*)(qp);
        aq[mi][1] = *(const bf16x8*)(qp + 32);
    }
    f32x4 oacc[2][4] = {};
    ushort* myP = Ps[w];

    int sr = tid >> 3;
    int sc = (tid & 7) * 8;
    for (int s0 = 0; s0 < 2048; s0 += 64) {
        uint4 k0g = *(const uint4*)(kbase + (size_t)(s0 + sr) * 1024 + sc);
        uint4 k1g = *(const uint4*)(kbase + (size_t)(s0 + 32 + sr) * 1024 + sc);
        uint4 v0g = *(const uint4*)(vtb + (size_t)sr * 2048 + s0 + sc);
        uint4 v1g = *(const uint4*)(vtb + (size_t)(32 + sr) * 2048 + s0 + sc);
        __syncthreads();
        *(uint4*)&Ks[sr * 72 + sc] = k0g;
        *(uint4*)&Ks[(32 + sr) * 72 + sc] = k1g;
        *(uint4*)&Vs[sr * 72 + sc] = v0g;
        *(uint4*)&Vs[(32 + sr) * 72 + sc] = v1g;
        __syncthreads();
        // S^T tiles: A = K rows (m=s), B = Q rows (n=t)
#pragma unroll
        for (int ssub = 0; ssub < 4; ssub++) {
            bf16x8 bk0 = *(const bf16x8*)&Ks[(ssub * 16 + l15) * 72 + q4 * 8];
            bf16x8 bk1 = *(const bf16x8*)&Ks[(ssub * 16 + l15) * 72 + 32 + q4 * 8];
#pragma unroll
            for (int mi = 0; mi < 2; mi++) {
                f32x4 d = {0.f, 0.f, 0.f, 0.f};
                d = mfma16(bk0, aq[mi][0], d);
                d = mfma16(bk1, aq[mi][1], d);
                float p0 = __expf(d[0] * 0.125f);
                float p1 = __expf(d[1] * 0.125f);
                float p2 = __expf(d[2] * 0.125f);
                float p3 = __expf(d[3] * 0.125f);
                uint2 uu;
                uu.x = pk2bf(p0, p1);
                uu.y = pk2bf(p2, p3);
                *(uint2*)&myP[(mi * 16 + l15) * 68 + ssub * 16 + q4 * 4] = uu;
            }
        }
        // PV: A = Pt (already A-layout), B = Vs rows (dh-major)
        bf16x8 bv[4][2];
#pragma unroll
        for (int ni = 0; ni < 4; ni++) {
            bv[ni][0] = *(const bf16x8*)&Vs[(ni * 16 + l15) * 72 + q4 * 8];
            bv[ni][1] = *(const bf16x8*)&Vs[(ni * 16 + l15) * 72 + 32 + q4 * 8];
        }
#pragma unroll
        for (int mi = 0; mi < 2; mi++) {
            bf16x8 ap0 = *(const bf16x8*)&myP[(mi * 16 + l15) * 68 + q4 * 8];
            bf16x8 ap1 = *(const bf16x8*)&myP[(mi * 16 + l15) * 68 + 32 + q4 * 8];
#pragma unroll
            for (int ni = 0; ni < 4; ni++) {
                oacc[mi][ni] = mfma16(ap0, bv[ni][0], oacc[mi][ni]);
                oacc[mi][ni] = mfma16(ap1, bv[ni][1], oacc[mi][ni]);
            }
        }
    }
#pragma unroll
    for (int mi = 0; mi < 2; mi++)
#pragma unroll
        for (int ni = 0; ni < 4; ni++)
#pragma unroll
            for (int r = 0; r < 4; r++) {
                int t = t_base + mi * 16 + q4 * 4 + r;
                float g = gelu_fast(oacc[mi][ni][r]) * 0.022097086912079608f;
                post[(size_t)(b * 2048 + t) * 1024 + h * 64 + ni * 16 + l15] = f2bf(g);
            }
}

// ---------------- LayerNorm with fused 4-plane bf16 split-K combine ----------------
__global__ __launch_bounds__(256) void ln_comb4(const ushort* __restrict__ parts,
                                                const float* __restrict__ bias,
                                                const float* __restrict__ res,
                                                const float* __restrict__ gw,
                                                const float* __restrict__ bw,
                                                ushort* __restrict__ outb,
                                                float* __restrict__ outf) {
    const size_t PLANE = (size_t)4096 * 1024;
    int row = blockIdx.x, tid = threadIdx.x;
    int lane = tid & 63, wid = tid >> 6;
    size_t off = (size_t)row * 1024 + tid * 4;
    float4 r = *(const float4*)(res + off);
    float4 bb = *(const float4*)(bias + tid * 4);
    float4 v;
    v.x = r.x + bb.x; v.y = r.y + bb.y; v.z = r.z + bb.z; v.w = r.w + bb.w;
#pragma unroll
    for (int p = 0; p < 4; p++) {
        ushort4 u = *(const ushort4*)(parts + p * PLANE + off);
        v.x += bf2f(u.x); v.y += bf2f(u.y); v.z += bf2f(u.z); v.w += bf2f(u.w);
    }
    float s = v.x + v.y + v.z + v.w;
    float ss = v.x * v.x + v.y * v.y + v.z * v.z + v.w * v.w;
    for (int m = 1; m < 64; m <<= 1) { s += __shfl_xor(s, m); ss += __shfl_xor(ss, m); }
    __shared__ float red[8];
    if (lane == 0) { red[wid] = s; red[wid + 4] = ss; }
    __syncthreads();
    s = red[0] + red[1] + red[2] + red[3];
    ss = red[4] + red[5] + red[6] + red[7];
    float mu = s * (1.f / 1024.f);
    float var = ss * (1.f / 1024.f) - mu * mu;
    float inv = rsqrtf(var + 1e-5f);
    float4 gv = *(const float4*)(gw + tid * 4);
    float4 bv = *(const float4*)(bw + tid * 4);
    float o0 = (v.x - mu) * inv * gv.x + bv.x;
    float o1 = (v.y - mu) * inv * gv.y + bv.y;
    float o2 = (v.z - mu) * inv * gv.z + bv.z;
    float o3 = (v.w - mu) * inv * gv.w + bv.w;
    if (outf) {
        float4 o; o.x = o0; o.y = o1; o.z = o2; o.w = o3;
        *(float4*)(outf + off) = o;
    }
    if (outb) {
        ushort4 o; o.x = f2bf(o0); o.y = f2bf(o1); o.z = f2bf(o2); o.w = f2bf(o3);
        *(ushort4*)(outb + off) = o;
    }
}

extern "C" void kernel_launch(void* const* d_in, const int* in_sizes, int n_in,
                              void* d_out, int out_size, void* d_ws, size_t ws_size,
                              hipStream_t stream) {
    const float* src  = (const float*)d_in[0];
    const float* w_in = (const float*)d_in[1];
    const float* b_in = (const float*)d_in[2];
    const float* w_o  = (const float*)d_in[3];
    const float* b_o  = (const float*)d_in[4];
    const float* w1   = (const float*)d_in[5];
    const float* b1   = (const float*)d_in[6];
    const float* w2   = (const float*)d_in[7];
    const float* b2   = (const float*)d_in[8];
    const float* g1   = (const float*)d_in[9];
    const float* be1  = (const float*)d_in[10];
    const float* g2   = (const float*)d_in[11];
    const float* be2  = (const float*)d_in[12];
    float* out = (float*)d_out;

    const size_t M = 4096;
    char* wsp = (char*)d_ws;
    size_t off = 0;
    auto alloc = [&](size_t bytes) -> void* {
        void* p = wsp + off;
        off = (off + bytes + 255) & ~(size_t)255;
        return p;
    };
    // NOTE: first five bf16 buffers must stay contiguous (cvt_all writes them flat).
    ushort* src_bf  = (ushort*)alloc(M * 1024 * 2);
    ushort* win_bf  = (ushort*)alloc(3072 * 1024 * 2);
    ushort* wout_bf = (ushort*)alloc(1024 * 1024 * 2);
    ushort* w1_bf   = (ushort*)alloc(4096 * 1024 * 2);
    ushort* w2_bf   = (ushort*)alloc((size_t)1024 * 4096 * 2);
    ushort* q_bf    = (ushort*)alloc(M * 1024 * 2);
    ushort* k_bf    = (ushort*)alloc(M * 1024 * 2);
    ushort* vt_bf   = (ushort*)alloc(M * 1024 * 2);
    ushort* post_bf = (ushort*)alloc(M * 1024 * 2);
    ushort* part    = (ushort*)alloc(4 * M * 1024 * 2);  // 4 bf16 split-K planes
    ushort* x_bf    = (ushort*)alloc(M * 1024 * 2);
    float*  x_f32   = (float*)alloc(M * 1024 * 4);
    ushort* h1_bf   = (ushort*)alloc(M * 4096 * 2);
    ushort* v_row   = part;   // alias: V row-major dead before out-proj writes part

    // 1) convert all fp32 inputs to bf16
    cvt_all<<<16384, 256, 0, stream>>>((const float4*)src, (const float4*)w_in,
                                       (const float4*)w_o, (const float4*)w1,
                                       (const float4*)w2, (ushort4*)src_bf);

    // 2) QKV projection
    gemm_bt<<<dim3(24, 32, 1), 256, 0, stream>>>(src_bf, win_bf, b_in, 4096, 3072, 1024, 1024, 0,
                                                 q_bf, k_bf, v_row);

    // 3) attention: colsum + fold/transpose V -> PV
    attn_colsum_foldv<<<512, 256, 0, stream>>>(q_bf, k_bf, v_row, vt_bf);
    attn_pv<<<512, 256, 0, stream>>>(q_bf, k_bf, vt_bf, post_bf);

    // 4) out-proj (split-K=4, bf16 partials) -> LN1 combine(+b_o, +src)
    gemm_bt<<<dim3(8, 32, 4), 256, 0, stream>>>(post_bf, wout_bf, b_o, 4096, 1024, 1024, 256, 3,
                                                part, nullptr, nullptr);
    ln_comb4<<<4096, 256, 0, stream>>>(part, b_o, src, g1, be1, x_bf, x_f32);

    // 5) FF: lin1+gelu ; lin2 (split-K=4, bf16 partials) -> LN2 combine(+b2, +x)
    gemm_bt<<<dim3(32, 32, 1), 256, 0, stream>>>(x_bf, w1_bf, b1, 4096, 4096, 1024, 1024, 2,
                                                 h1_bf, nullptr, nullptr);
    gemm_bt<<<dim3(8, 32, 4), 256, 0, stream>>>(h1_bf, w2_bf, b2, 4096, 1024, 4096, 1024, 3,
                                                part, nullptr, nullptr);
    ln_comb4<<<4096, 256, 0, stream>>>(part, b2, x_f32, g2, be2, nullptr, out);
}

// Round 7
// 469.915 us; speedup vs baseline: 1.0262x; 1.0262x over previous
//
#include <hip/hip_runtime.h>
#include <hip/hip_bf16.h>
#include <math.h>

// Round 6: (a) gemm XCD slabs made square-ish (gx x gy factorization) to cut
// weight-matrix duplication across XCD L2s; (b) attention K/V/Q staging moved
// to global_load_lds with XOR-swizzled unpadded LDS tiles (2-way reads, free).
// R5's packed-P operand-swap attn_pv retained.

using bf16x8 = __attribute__((ext_vector_type(8))) short;
using f32x4  = __attribute__((ext_vector_type(4))) float;

__device__ inline f32x4 mfma16(bf16x8 a, bf16x8 b, f32x4 c) {
    return __builtin_amdgcn_mfma_f32_16x16x32_bf16(a, b, c, 0, 0, 0);
}

__device__ inline ushort f2bf(float f) {
    union { float f; unsigned u; } x; x.f = f;
    unsigned r = x.u + 0x7fffu + ((x.u >> 16) & 1u);
    return (ushort)(r >> 16);
}

__device__ inline float bf2f(ushort u) {
    union { unsigned u; float f; } x; x.u = ((unsigned)u) << 16; return x.f;
}

// pack two floats -> two bf16 (v_cvt_pk_bf16_f32 on gfx950)
__device__ inline unsigned pk2bf(float a, float b) {
    __hip_bfloat162 h = __float22bfloat162_rn(float2{a, b});
    union { __hip_bfloat162 h; unsigned u; } x; x.h = h;
    return x.u;
}

// tanh-form gelu: v * sigmoid(1.59577v + 0.071355v^3); max |err| vs erf ~3e-3
__device__ inline float gelu_fast(float v) {
    float u = v * (1.5957691216f + 0.0713548162f * v * v);
    float e = __expf(u);
    return v * (e / (e + 1.0f));
}

// async 16B global -> LDS (wave-uniform LDS base + lane*16)
__device__ __forceinline__ void gl2lds16(const ushort* g, ushort* l) {
    __builtin_amdgcn_global_load_lds(
        (const __attribute__((address_space(1))) unsigned int*)g,
        (__attribute__((address_space(3))) unsigned int*)l,
        16, 0, 0);
}

// ---------------- merged fp32 -> bf16 convert ----------------
__global__ __launch_bounds__(256) void cvt_all(const float4* __restrict__ s0,
                                               const float4* __restrict__ s1,
                                               const float4* __restrict__ s2,
                                               const float4* __restrict__ s3,
                                               const float4* __restrict__ s4,
                                               ushort4* __restrict__ out) {
    int i = blockIdx.x * 256 + threadIdx.x;
    const float4* p;
    int off;
    if (i < 1048576)      { p = s0; off = i; }
    else if (i < 1835008) { p = s1; off = i - 1048576; }
    else if (i < 2097152) { p = s2; off = i - 1835008; }
    else if (i < 3145728) { p = s3; off = i - 2097152; }
    else                  { p = s4; off = i - 3145728; }
    float4 v = p[off];
    ushort4 o;
    o.x = f2bf(v.x); o.y = f2bf(v.y); o.z = f2bf(v.z); o.w = f2bf(v.w);
    out[i] = o;
}

// ---------------- GEMM: out[M,N] = A[M,K] @ Bw[N,K]^T (+ bias) ----------------
// mode 0: QKV epilogue -> ob0 (Q), ob1 (K), ob2 (V row-major); +bias
// mode 2: bf16 out = gelu(acc + bias)
// mode 3: bf16 partial: ob0[z*M*N + idx] = acc (bias added in LN combine)
// gx: XCD slab factorization (8 = gx*gy); slab c covers a (Nx/gx)x(Ny/gy) tile region.
__global__ __launch_bounds__(256) void gemm_bt(
    const ushort* __restrict__ A, const ushort* __restrict__ Bw,
    const float* __restrict__ bias, int M, int N, int K, int kLen, int mode, int gx,
    ushort* __restrict__ ob0, ushort* __restrict__ ob1, ushort* __restrict__ ob2) {
    __shared__ ushort As[2][128 * 32];
    __shared__ ushort Bs[2][128 * 32];
    int tid = threadIdx.x, lane = tid & 63, w = tid >> 6;
    int wm = w >> 1, wn = w & 1;

    // XCD-aware swizzle, square-ish slabs
    int Nx = gridDim.x, Ny = gridDim.y;
    int bx = blockIdx.x, by = blockIdx.y;
    int gy = 8 / gx;
    if ((Nx % gx) == 0 && (Ny % gy) == 0 && ((Nx * Ny) & 7) == 0) {
        int Sx = Nx / gx, Sy = Ny / gy;
        int i = bx + Nx * by;
        int c = i & 7, j = i >> 3;
        int cx = c % gx, cy = c / gx;
        bx = cx * Sx + j % Sx;
        by = cy * Sy + (j / Sx) % Sy;
    }
    int bm = by * 128, bn = bx * 128;
    int kz = blockIdx.z;
    int q4 = lane >> 4, l15 = lane & 15;
    f32x4 acc[4][4] = {};

    int srow = w * 16 + (lane >> 2);
    int scg = lane & 3;
    const ushort* Ab = A + (size_t)bm * K + (size_t)kz * kLen;
    const ushort* Bb = Bw + (size_t)bn * K + (size_t)kz * kLen;
    const ushort* gA0 = Ab + (size_t)srow * K + scg * 8;
    const ushort* gA1 = Ab + (size_t)(64 + srow) * K + scg * 8;
    const ushort* gB0 = Bb + (size_t)srow * K + scg * 8;
    const ushort* gB1 = Bb + (size_t)(64 + srow) * K + scg * 8;
    ushort* lA00 = As[0] + w * 512;
    ushort* lA10 = As[0] + 2048 + w * 512;
    ushort* lB00 = Bs[0] + w * 512;
    ushort* lB10 = Bs[0] + 2048 + w * 512;
    ushort* lA01 = As[1] + w * 512;
    ushort* lA11 = As[1] + 2048 + w * 512;
    ushort* lB01 = Bs[1] + w * 512;
    ushort* lB11 = Bs[1] + 2048 + w * 512;

    const ushort* aB[2] = { &As[0][(wm * 64 + l15) * 32 + q4 * 8],
                            &As[1][(wm * 64 + l15) * 32 + q4 * 8] };
    const ushort* bB[2] = { &Bs[0][(wn * 64 + l15) * 32 + q4 * 8],
                            &Bs[1][(wn * 64 + l15) * 32 + q4 * 8] };

    for (int k0 = 0; k0 < kLen; k0 += 64) {
        __syncthreads();
        gl2lds16(gA0 + k0, lA00);
        gl2lds16(gA1 + k0, lA10);
        gl2lds16(gB0 + k0, lB00);
        gl2lds16(gB1 + k0, lB10);
        gl2lds16(gA0 + k0 + 32, lA01);
        gl2lds16(gA1 + k0 + 32, lA11);
        gl2lds16(gB0 + k0 + 32, lB01);
        gl2lds16(gB1 + k0 + 32, lB11);
        __syncthreads();
#pragma unroll
        for (int u = 0; u < 2; u++) {
            bf16x8 af[4], bfr[4];
#pragma unroll
            for (int mi = 0; mi < 4; mi++)
                af[mi] = *(const bf16x8*)(aB[u] + mi * 512);
#pragma unroll
            for (int ni = 0; ni < 4; ni++)
                bfr[ni] = *(const bf16x8*)(bB[u] + ni * 512);
#pragma unroll
            for (int mi = 0; mi < 4; mi++)
#pragma unroll
                for (int ni = 0; ni < 4; ni++)
                    acc[mi][ni] = mfma16(af[mi], bfr[ni], acc[mi][ni]);
        }
    }

    int r0 = bm + wm * 64, c0 = bn + wn * 64;
#pragma unroll
    for (int mi = 0; mi < 4; mi++) {
#pragma unroll
        for (int ni = 0; ni < 4; ni++) {
            int colg = c0 + ni * 16 + l15;
            float bv = (mode == 3) ? 0.f : bias[colg];
#pragma unroll
            for (int r = 0; r < 4; r++) {
                int rowg = r0 + mi * 16 + q4 * 4 + r;
                float v = acc[mi][ni][r] + bv;
                if (mode == 0) {
                    if (colg < 1024) {
                        ob0[(size_t)rowg * 1024 + colg] = f2bf(v);
                    } else if (colg < 2048) {
                        ob1[(size_t)rowg * 1024 + (colg - 1024)] = f2bf(v);
                    } else {
                        ob2[(size_t)rowg * 1024 + (colg - 2048)] = f2bf(v);
                    }
                } else if (mode == 2) {
                    ob0[(size_t)rowg * N + colg] = f2bf(gelu_fast(v));
                } else {
                    ob0[(size_t)kz * M * N + (size_t)rowg * N + colg] = f2bf(v);
                }
            }
        }
    }
}

// ---------------- attention pass A + V fold/transpose ----------------
// Q staged via global_load_lds into XOR-swizzled 64x64 tile (stride 64, no pad):
// LDS[r][cb] = G[r][cb ^ (r&7)] (16B blocks). Fragment reads are 2-way (free).
__global__ __launch_bounds__(256) void attn_colsum_foldv(const ushort* __restrict__ qb,
                                                         const ushort* __restrict__ kb,
                                                         const ushort* __restrict__ vrow,
                                                         ushort* __restrict__ vt) {
    __shared__ ushort Qs[64 * 72];   // staging uses first 64*64 (stride 64); fold uses stride 72
    __shared__ float NinvS[128];
    int tid = threadIdx.x, lane = tid & 63, w = tid >> 6;
    int bh = blockIdx.x >> 4, sblk = blockIdx.x & 15;
    int b = bh >> 4, h = bh & 15;
    int q4 = lane >> 4, l15 = lane & 15;
    const ushort* qbase = qb + (size_t)(b * 2048) * 1024 + h * 64;
    const ushort* kbase = kb + (size_t)(b * 2048) * 1024 + h * 64;
    int s_base = sblk * 128 + w * 32;

    bf16x8 ka[2][2];
#pragma unroll
    for (int mi = 0; mi < 2; mi++) {
        const ushort* kp = kbase + (size_t)(s_base + mi * 16 + l15) * 1024 + q4 * 8;
        ka[mi][0] = *(const bf16x8*)(kp);
        ka[mi][1] = *(const bf16x8*)(kp + 32);
    }
    float acc[2][4] = {};

    int rl = lane >> 3;                       // 0..7
    int cswz = (((lane & 7) ^ rl) << 3);      // swizzled 8-elem col offset
    int swf = l15 & 7;                        // fragment-read swizzle key
    int c0s = (q4 ^ swf) << 3;                // dh 0-31 block
    int c1s = ((q4 + 4) ^ swf) << 3;          // dh 32-63 block
    for (int t0 = 0; t0 < 2048; t0 += 64) {
        __syncthreads();
        gl2lds16(qbase + (size_t)(t0 + w * 16 + rl) * 1024 + cswz, Qs + (w * 16) * 64);
        gl2lds16(qbase + (size_t)(t0 + w * 16 + 8 + rl) * 1024 + cswz, Qs + (w * 16 + 8) * 64);
        __syncthreads();
#pragma unroll
        for (int tsub = 0; tsub < 4; tsub++) {
            int rQ = (tsub * 16 + l15) * 64;
            bf16x8 bq0 = *(const bf16x8*)&Qs[rQ + c0s];
            bf16x8 bq1 = *(const bf16x8*)&Qs[rQ + c1s];
#pragma unroll
            for (int mi = 0; mi < 2; mi++) {
                f32x4 d = {0.f, 0.f, 0.f, 0.f};
                d = mfma16(ka[mi][0], bq0, d);
                d = mfma16(ka[mi][1], bq1, d);
#pragma unroll
                for (int r = 0; r < 4; r++)
                    acc[mi][r] += __expf(d[r] * 0.125f);
            }
        }
    }
#pragma unroll
    for (int mi = 0; mi < 2; mi++)
#pragma unroll
        for (int r = 0; r < 4; r++) {
            float v = acc[mi][r];
            v += __shfl_xor(v, 1); v += __shfl_xor(v, 2);
            v += __shfl_xor(v, 4); v += __shfl_xor(v, 8);
            if (l15 == 0)
                NinvS[w * 32 + mi * 16 + q4 * 4 + r] = 1.f / v;
        }

    // ---- fold ninv into V and transpose to vt[bh][dh][s] (two 64-s batches) ----
    int sl = tid >> 3, dh8 = (tid & 7) * 8;
#pragma unroll
    for (int batch = 0; batch < 2; batch++) {
        int bs = sblk * 128 + batch * 64;
        __syncthreads();
#pragma unroll
        for (int rep = 0; rep < 2; rep++) {
            int s = sl + rep * 32;
            float n = NinvS[batch * 64 + s];
            const ushort* p = vrow + (size_t)(b * 2048 + bs + s) * 1024 + h * 64 + dh8;
            ushort4 u0 = ((const ushort4*)p)[0];
            ushort4 u1 = ((const ushort4*)p)[1];
            ushort4 o0, o1;
            o0.x = f2bf(bf2f(u0.x) * n); o0.y = f2bf(bf2f(u0.y) * n);
            o0.z = f2bf(bf2f(u0.z) * n); o0.w = f2bf(bf2f(u0.w) * n);
            o1.x = f2bf(bf2f(u1.x) * n); o1.y = f2bf(bf2f(u1.y) * n);
            o1.z = f2bf(bf2f(u1.z) * n); o1.w = f2bf(bf2f(u1.w) * n);
            *(ushort4*)&Qs[s * 72 + dh8] = o0;
            *(ushort4*)&Qs[s * 72 + dh8 + 4] = o1;
        }
        __syncthreads();
        int dhl = tid >> 3, soff = (tid & 7) * 8;
#pragma unroll
        for (int rep = 0; rep < 2; rep++) {
            int d = dhl + rep * 32;
            ushort tmp[8];
#pragma unroll
            for (int j = 0; j < 8; j++) tmp[j] = Qs[(soff + j) * 72 + d];
            *(uint4*)(vt + ((size_t)bh * 64 + d) * 2048 + bs + soff) = *(uint4*)tmp;
        }
    }
}

// ---------------- attention pass B: post = gelu(exp(QK/8) @ Vscaled)/sqrt(S) ----------------
// K/V staged via global_load_lds into XOR-swizzled 64x64 tiles; P via packed
// cvt + ds_write_b64 in PV-A-operand layout (operand-swapped QK^T).
__global__ __launch_bounds__(256) void attn_pv(const ushort* __restrict__ qb,
                                               const ushort* __restrict__ kb,
                                               const ushort* __restrict__ vt,
                                               ushort* __restrict__ post) {
    __shared__ ushort Ks[64 * 64];
    __shared__ ushort Vs[64 * 64];
    __shared__ ushort Ps[4][32 * 68];       // per-wave Pt[t][s], stride 68
    int tid = threadIdx.x, lane = tid & 63, w = tid >> 6;
    int bh = blockIdx.x >> 4, tblk = blockIdx.x & 15;
    int b = bh >> 4, h = bh & 15;
    int q4 = lane >> 4, l15 = lane & 15;
    const ushort* qbase = qb + (size_t)(b * 2048) * 1024 + h * 64;
    const ushort* kbase = kb + (size_t)(b * 2048) * 1024 + h * 64;
    const ushort* vtb = vt + (size_t)bh * 64 * 2048;
    int t_base = tblk * 128 + w * 32;

    bf16x8 aq[2][2];
#pragma unroll
    for (int mi = 0; mi < 2; mi++) {
        const ushort* qp = qbase + (size_t)(t_base + mi * 16 + l15) * 1024 + q4 * 8;
        aq[mi][0] = *(const bf16x8*)(qp);
        aq[mi][1] = *(const bf16x8*)(qp + 32);
    }
    f32x4 oacc[2][4] = {};
    ushort* myP = Ps[w];

    int rl = lane >> 3;
    int cswz = (((lane & 7) ^ rl) << 3);
    int swf = l15 & 7;
    int c0s = (q4 ^ swf) << 3;
    int c1s = ((q4 + 4) ^ swf) << 3;
    for (int s0 = 0; s0 < 2048; s0 += 64) {
        __syncthreads();
        gl2lds16(kbase + (size_t)(s0 + w * 16 + rl) * 1024 + cswz, Ks + (w * 16) * 64);
        gl2lds16(kbase + (size_t)(s0 + w * 16 + 8 + rl) * 1024 + cswz, Ks + (w * 16 + 8) * 64);
        gl2lds16(vtb + (size_t)(w * 16 + rl) * 2048 + s0 + cswz, Vs + (w * 16) * 64);
        gl2lds16(vtb + (size_t)(w * 16 + 8 + rl) * 2048 + s0 + cswz, Vs + (w * 16 + 8) * 64);
        __syncthreads();
        // S^T tiles: A = K rows (m=s), B = Q rows (n=t)
#pragma unroll
        for (int ssub = 0; ssub < 4; ssub++) {
            int rA = (ssub * 16 + l15) * 64;
            bf16x8 bk0 = *(const bf16x8*)&Ks[rA + c0s];
            bf16x8 bk1 = *(const bf16x8*)&Ks[rA + c1s];
#pragma unroll
            for (int mi = 0; mi < 2; mi++) {
                f32x4 d = {0.f, 0.f, 0.f, 0.f};
                d = mfma16(bk0, aq[mi][0], d);
                d = mfma16(bk1, aq[mi][1], d);
                float p0 = __expf(d[0] * 0.125f);
                float p1 = __expf(d[1] * 0.125f);
                float p2 = __expf(d[2] * 0.125f);
                float p3 = __expf(d[3] * 0.125f);
                uint2 uu;
                uu.x = pk2bf(p0, p1);
                uu.y = pk2bf(p2, p3);
                *(uint2*)&myP[(mi * 16 + l15) * 68 + ssub * 16 + q4 * 4] = uu;
            }
        }
        // PV: A = Pt (A-layout), B = Vs rows (dh-major, swizzled)
#pragma unroll
        for (int mi = 0; mi < 2; mi++) {
            bf16x8 ap0 = *(const bf16x8*)&myP[(mi * 16 + l15) * 68 + q4 * 8];
            bf16x8 ap1 = *(const bf16x8*)&myP[(mi * 16 + l15) * 68 + 32 + q4 * 8];
#pragma unroll
            for (int ni = 0; ni < 4; ni++) {
                int rV = (ni * 16 + l15) * 64;
                bf16x8 bv0 = *(const bf16x8*)&Vs[rV + c0s];
                bf16x8 bv1 = *(const bf16x8*)&Vs[rV + c1s];
                oacc[mi][ni] = mfma16(ap0, bv0, oacc[mi][ni]);
                oacc[mi][ni] = mfma16(ap1, bv1, oacc[mi][ni]);
            }
        }
    }
#pragma unroll
    for (int mi = 0; mi < 2; mi++)
#pragma unroll
        for (int ni = 0; ni < 4; ni++)
#pragma unroll
            for (int r = 0; r < 4; r++) {
                int t = t_base + mi * 16 + q4 * 4 + r;
                float g = gelu_fast(oacc[mi][ni][r]) * 0.022097086912079608f;
                post[(size_t)(b * 2048 + t) * 1024 + h * 64 + ni * 16 + l15] = f2bf(g);
            }
}

// ---------------- LayerNorm with fused 4-plane bf16 split-K combine ----------------
__global__ __launch_bounds__(256) void ln_comb4(const ushort* __restrict__ parts,
                                                const float* __restrict__ bias,
                                                const float* __restrict__ res,
                                                const float* __restrict__ gw,
                                                const float* __restrict__ bw,
                                                ushort* __restrict__ outb,
                                                float* __restrict__ outf) {
    const size_t PLANE = (size_t)4096 * 1024;
    int row = blockIdx.x, tid = threadIdx.x;
    int lane = tid & 63, wid = tid >> 6;
    size_t off = (size_t)row * 1024 + tid * 4;
    float4 r = *(const float4*)(res + off);
    float4 bb = *(const float4*)(bias + tid * 4);
    float4 v;
    v.x = r.x + bb.x; v.y = r.y + bb.y; v.z = r.z + bb.z; v.w = r.w + bb.w;
#pragma unroll
    for (int p = 0; p < 4; p++) {
        ushort4 u = *(const ushort4*)(parts + p * PLANE + off);
        v.x += bf2f(u.x); v.y += bf2f(u.y); v.z += bf2f(u.z); v.w += bf2f(u.w);
    }
    float s = v.x + v.y + v.z + v.w;
    float ss = v.x * v.x + v.y * v.y + v.z * v.z + v.w * v.w;
    for (int m = 1; m < 64; m <<= 1) { s += __shfl_xor(s, m); ss += __shfl_xor(ss, m); }
    __shared__ float red[8];
    if (lane == 0) { red[wid] = s; red[wid + 4] = ss; }
    __syncthreads();
    s = red[0] + red[1] + red[2] + red[3];
    ss = red[4] + red[5] + red[6] + red[7];
    float mu = s * (1.f / 1024.f);
    float var = ss * (1.f / 1024.f) - mu * mu;
    float inv = rsqrtf(var + 1e-5f);
    float4 gv = *(const float4*)(gw + tid * 4);
    float4 bv = *(const float4*)(bw + tid * 4);
    float o0 = (v.x - mu) * inv * gv.x + bv.x;
    float o1 = (v.y - mu) * inv * gv.y + bv.y;
    float o2 = (v.z - mu) * inv * gv.z + bv.z;
    float o3 = (v.w - mu) * inv * gv.w + bv.w;
    if (outf) {
        float4 o; o.x = o0; o.y = o1; o.z = o2; o.w = o3;
        *(float4*)(outf + off) = o;
    }
    if (outb) {
        ushort4 o; o.x = f2bf(o0); o.y = f2bf(o1); o.z = f2bf(o2); o.w = f2bf(o3);
        *(ushort4*)(outb + off) = o;
    }
}

extern "C" void kernel_launch(void* const* d_in, const int* in_sizes, int n_in,
                              void* d_out, int out_size, void* d_ws, size_t ws_size,
                              hipStream_t stream) {
    const float* src  = (const float*)d_in[0];
    const float* w_in = (const float*)d_in[1];
    const float* b_in = (const float*)d_in[2];
    const float* w_o  = (const float*)d_in[3];
    const float* b_o  = (const float*)d_in[4];
    const float* w1   = (const float*)d_in[5];
    const float* b1   = (const float*)d_in[6];
    const float* w2   = (const float*)d_in[7];
    const float* b2   = (const float*)d_in[8];
    const float* g1   = (const float*)d_in[9];
    const float* be1  = (const float*)d_in[10];
    const float* g2   = (const float*)d_in[11];
    const float* be2  = (const float*)d_in[12];
    float* out = (float*)d_out;

    const size_t M = 4096;
    char* wsp = (char*)d_ws;
    size_t off = 0;
    auto alloc = [&](size_t bytes) -> void* {
        void* p = wsp + off;
        off = (off + bytes + 255) & ~(size_t)255;
        return p;
    };
    // NOTE: first five bf16 buffers must stay contiguous (cvt_all writes them flat).
    ushort* src_bf  = (ushort*)alloc(M * 1024 * 2);
    ushort* win_bf  = (ushort*)alloc(3072 * 1024 * 2);
    ushort* wout_bf = (ushort*)alloc(1024 * 1024 * 2);
    ushort* w1_bf   = (ushort*)alloc(4096 * 1024 * 2);
    ushort* w2_bf   = (ushort*)alloc((size_t)1024 * 4096 * 2);
    ushort* q_bf    = (ushort*)alloc(M * 1024 * 2);
    ushort* k_bf    = (ushort*)alloc(M * 1024 * 2);
    ushort* vt_bf   = (ushort*)alloc(M * 1024 * 2);
    ushort* post_bf = (ushort*)alloc(M * 1024 * 2);
    ushort* part    = (ushort*)alloc(4 * M * 1024 * 2);  // 4 bf16 split-K planes
    ushort* x_bf    = (ushort*)alloc(M * 1024 * 2);
    float*  x_f32   = (float*)alloc(M * 1024 * 4);
    ushort* h1_bf   = (ushort*)alloc(M * 4096 * 2);
    ushort* v_row   = part;   // alias: V row-major dead before out-proj writes part

    // 1) convert all fp32 inputs to bf16
    cvt_all<<<16384, 256, 0, stream>>>((const float4*)src, (const float4*)w_in,
                                       (const float4*)w_o, (const float4*)w1,
                                       (const float4*)w2, (ushort4*)src_bf);

    // 2) QKV projection (slab 12x8)
    gemm_bt<<<dim3(24, 32, 1), 256, 0, stream>>>(src_bf, win_bf, b_in, 4096, 3072, 1024, 1024, 0, 2,
                                                 q_bf, k_bf, v_row);

    // 3) attention: colsum + fold/transpose V -> PV
    attn_colsum_foldv<<<512, 256, 0, stream>>>(q_bf, k_bf, v_row, vt_bf);
    attn_pv<<<512, 256, 0, stream>>>(q_bf, k_bf, vt_bf, post_bf);

    // 4) out-proj (split-K=4, bf16 partials, slab 8x4) -> LN1 combine(+b_o, +src)
    gemm_bt<<<dim3(8, 32, 4), 256, 0, stream>>>(post_bf, wout_bf, b_o, 4096, 1024, 1024, 256, 3, 1,
                                                part, nullptr, nullptr);
    ln_comb4<<<4096, 256, 0, stream>>>(part, b_o, src, g1, be1, x_bf, x_f32);

    // 5) FF: lin1+gelu (slab 16x8) ; lin2 (split-K=4, slab 8x4) -> LN2 combine(+b2, +x)
    gemm_bt<<<dim3(32, 32, 1), 256, 0, stream>>>(x_bf, w1_bf, b1, 4096, 4096, 1024, 1024, 2, 2,
                                                 h1_bf, nullptr, nullptr);
    gemm_bt<<<dim3(8, 32, 4), 256, 0, stream>>>(h1_bf, w2_bf, b2, 4096, 1024, 4096, 1024, 3, 1,
                                                part, nullptr, nullptr);
    ln_comb4<<<4096, 256, 0, stream>>>(part, b2, x_f32, g2, be2, nullptr, out);
}

// Round 8
// 465.779 us; speedup vs baseline: 1.0353x; 1.0089x over previous
//
#include <hip/hip_runtime.h>
#include <hip/hip_bf16.h>
#include <math.h>

// Round 7: attention occupancy fix — split reduction dims across blocks.
// attn_pv: s-split x2 (grid 1024, bf16 partial O planes) + attn_combine
// (gelu(p0+p1)/sqrt(S)). colsum: t-split x2 (fp32 partial sums) + separate
// foldv (ninv=1/(c0+c1) fold + V transpose). GEMM/LN unchanged from R6.

using bf16x8 = __attribute__((ext_vector_type(8))) short;
using f32x4  = __attribute__((ext_vector_type(4))) float;

__device__ inline f32x4 mfma16(bf16x8 a, bf16x8 b, f32x4 c) {
    return __builtin_amdgcn_mfma_f32_16x16x32_bf16(a, b, c, 0, 0, 0);
}

__device__ inline ushort f2bf(float f) {
    union { float f; unsigned u; } x; x.f = f;
    unsigned r = x.u + 0x7fffu + ((x.u >> 16) & 1u);
    return (ushort)(r >> 16);
}

__device__ inline float bf2f(ushort u) {
    union { unsigned u; float f; } x; x.u = ((unsigned)u) << 16; return x.f;
}

// pack two floats -> two bf16 (v_cvt_pk_bf16_f32 on gfx950)
__device__ inline unsigned pk2bf(float a, float b) {
    __hip_bfloat162 h = __float22bfloat162_rn(float2{a, b});
    union { __hip_bfloat162 h; unsigned u; } x; x.h = h;
    return x.u;
}

// tanh-form gelu: v * sigmoid(1.59577v + 0.071355v^3); max |err| vs erf ~3e-3
__device__ inline float gelu_fast(float v) {
    float u = v * (1.5957691216f + 0.0713548162f * v * v);
    float e = __expf(u);
    return v * (e / (e + 1.0f));
}

// async 16B global -> LDS (wave-uniform LDS base + lane*16)
__device__ __forceinline__ void gl2lds16(const ushort* g, ushort* l) {
    __builtin_amdgcn_global_load_lds(
        (const __attribute__((address_space(1))) unsigned int*)g,
        (__attribute__((address_space(3))) unsigned int*)l,
        16, 0, 0);
}

// ---------------- merged fp32 -> bf16 convert ----------------
__global__ __launch_bounds__(256) void cvt_all(const float4* __restrict__ s0,
                                               const float4* __restrict__ s1,
                                               const float4* __restrict__ s2,
                                               const float4* __restrict__ s3,
                                               const float4* __restrict__ s4,
                                               ushort4* __restrict__ out) {
    int i = blockIdx.x * 256 + threadIdx.x;
    const float4* p;
    int off;
    if (i < 1048576)      { p = s0; off = i; }
    else if (i < 1835008) { p = s1; off = i - 1048576; }
    else if (i < 2097152) { p = s2; off = i - 1835008; }
    else if (i < 3145728) { p = s3; off = i - 2097152; }
    else                  { p = s4; off = i - 3145728; }
    float4 v = p[off];
    ushort4 o;
    o.x = f2bf(v.x); o.y = f2bf(v.y); o.z = f2bf(v.z); o.w = f2bf(v.w);
    out[i] = o;
}

// ---------------- GEMM: out[M,N] = A[M,K] @ Bw[N,K]^T (+ bias) ----------------
__global__ __launch_bounds__(256) void gemm_bt(
    const ushort* __restrict__ A, const ushort* __restrict__ Bw,
    const float* __restrict__ bias, int M, int N, int K, int kLen, int mode, int gx,
    ushort* __restrict__ ob0, ushort* __restrict__ ob1, ushort* __restrict__ ob2) {
    __shared__ ushort As[2][128 * 32];
    __shared__ ushort Bs[2][128 * 32];
    int tid = threadIdx.x, lane = tid & 63, w = tid >> 6;
    int wm = w >> 1, wn = w & 1;

    int Nx = gridDim.x, Ny = gridDim.y;
    int bx = blockIdx.x, by = blockIdx.y;
    int gy = 8 / gx;
    if ((Nx % gx) == 0 && (Ny % gy) == 0 && ((Nx * Ny) & 7) == 0) {
        int Sx = Nx / gx, Sy = Ny / gy;
        int i = bx + Nx * by;
        int c = i & 7, j = i >> 3;
        int cx = c % gx, cy = c / gx;
        bx = cx * Sx + j % Sx;
        by = cy * Sy + (j / Sx) % Sy;
    }
    int bm = by * 128, bn = bx * 128;
    int kz = blockIdx.z;
    int q4 = lane >> 4, l15 = lane & 15;
    f32x4 acc[4][4] = {};

    int srow = w * 16 + (lane >> 2);
    int scg = lane & 3;
    const ushort* Ab = A + (size_t)bm * K + (size_t)kz * kLen;
    const ushort* Bb = Bw + (size_t)bn * K + (size_t)kz * kLen;
    const ushort* gA0 = Ab + (size_t)srow * K + scg * 8;
    const ushort* gA1 = Ab + (size_t)(64 + srow) * K + scg * 8;
    const ushort* gB0 = Bb + (size_t)srow * K + scg * 8;
    const ushort* gB1 = Bb + (size_t)(64 + srow) * K + scg * 8;
    ushort* lA00 = As[0] + w * 512;
    ushort* lA10 = As[0] + 2048 + w * 512;
    ushort* lB00 = Bs[0] + w * 512;
    ushort* lB10 = Bs[0] + 2048 + w * 512;
    ushort* lA01 = As[1] + w * 512;
    ushort* lA11 = As[1] + 2048 + w * 512;
    ushort* lB01 = Bs[1] + w * 512;
    ushort* lB11 = Bs[1] + 2048 + w * 512;

    const ushort* aB[2] = { &As[0][(wm * 64 + l15) * 32 + q4 * 8],
                            &As[1][(wm * 64 + l15) * 32 + q4 * 8] };
    const ushort* bB[2] = { &Bs[0][(wn * 64 + l15) * 32 + q4 * 8],
                            &Bs[1][(wn * 64 + l15) * 32 + q4 * 8] };

    for (int k0 = 0; k0 < kLen; k0 += 64) {
        __syncthreads();
        gl2lds16(gA0 + k0, lA00);
        gl2lds16(gA1 + k0, lA10);
        gl2lds16(gB0 + k0, lB00);
        gl2lds16(gB1 + k0, lB10);
        gl2lds16(gA0 + k0 + 32, lA01);
        gl2lds16(gA1 + k0 + 32, lA11);
        gl2lds16(gB0 + k0 + 32, lB01);
        gl2lds16(gB1 + k0 + 32, lB11);
        __syncthreads();
#pragma unroll
        for (int u = 0; u < 2; u++) {
            bf16x8 af[4], bfr[4];
#pragma unroll
            for (int mi = 0; mi < 4; mi++)
                af[mi] = *(const bf16x8*)(aB[u] + mi * 512);
#pragma unroll
            for (int ni = 0; ni < 4; ni++)
                bfr[ni] = *(const bf16x8*)(bB[u] + ni * 512);
#pragma unroll
            for (int mi = 0; mi < 4; mi++)
#pragma unroll
                for (int ni = 0; ni < 4; ni++)
                    acc[mi][ni] = mfma16(af[mi], bfr[ni], acc[mi][ni]);
        }
    }

    int r0 = bm + wm * 64, c0 = bn + wn * 64;
#pragma unroll
    for (int mi = 0; mi < 4; mi++) {
#pragma unroll
        for (int ni = 0; ni < 4; ni++) {
            int colg = c0 + ni * 16 + l15;
            float bv = (mode == 3) ? 0.f : bias[colg];
#pragma unroll
            for (int r = 0; r < 4; r++) {
                int rowg = r0 + mi * 16 + q4 * 4 + r;
                float v = acc[mi][ni][r] + bv;
                if (mode == 0) {
                    if (colg < 1024) {
                        ob0[(size_t)rowg * 1024 + colg] = f2bf(v);
                    } else if (colg < 2048) {
                        ob1[(size_t)rowg * 1024 + (colg - 1024)] = f2bf(v);
                    } else {
                        ob2[(size_t)rowg * 1024 + (colg - 2048)] = f2bf(v);
                    }
                } else if (mode == 2) {
                    ob0[(size_t)rowg * N + colg] = f2bf(gelu_fast(v));
                } else {
                    ob0[(size_t)kz * M * N + (size_t)rowg * N + colg] = f2bf(v);
                }
            }
        }
    }
}

// ---------------- attention pass A (t-split): partial colsum[s] ----------------
// Block = (bh, sblk, thalf). csum[th][bh][2048] = sum over its 1024 t of exp(q.k/8).
__global__ __launch_bounds__(256) void attn_colsum_part(const ushort* __restrict__ qb,
                                                        const ushort* __restrict__ kb,
                                                        float* __restrict__ csum) {
    __shared__ ushort Qs[64 * 64];
    int tid = threadIdx.x, lane = tid & 63, w = tid >> 6;
    int id = blockIdx.x;
    int th = id & 1, sblk = (id >> 1) & 15, bh = id >> 5;
    int b = bh >> 4, h = bh & 15;
    int q4 = lane >> 4, l15 = lane & 15;
    const ushort* qbase = qb + (size_t)(b * 2048) * 1024 + h * 64;
    const ushort* kbase = kb + (size_t)(b * 2048) * 1024 + h * 64;
    int s_base = sblk * 128 + w * 32;

    bf16x8 ka[2][2];
#pragma unroll
    for (int mi = 0; mi < 2; mi++) {
        const ushort* kp = kbase + (size_t)(s_base + mi * 16 + l15) * 1024 + q4 * 8;
        ka[mi][0] = *(const bf16x8*)(kp);
        ka[mi][1] = *(const bf16x8*)(kp + 32);
    }
    float acc[2][4] = {};

    int rl = lane >> 3;
    int cswz = (((lane & 7) ^ rl) << 3);
    int swf = l15 & 7;
    int c0s = (q4 ^ swf) << 3;
    int c1s = ((q4 + 4) ^ swf) << 3;
    int tEnd = th * 1024 + 1024;
    for (int t0 = th * 1024; t0 < tEnd; t0 += 64) {
        __syncthreads();
        gl2lds16(qbase + (size_t)(t0 + w * 16 + rl) * 1024 + cswz, Qs + (w * 16) * 64);
        gl2lds16(qbase + (size_t)(t0 + w * 16 + 8 + rl) * 1024 + cswz, Qs + (w * 16 + 8) * 64);
        __syncthreads();
#pragma unroll
        for (int tsub = 0; tsub < 4; tsub++) {
            int rQ = (tsub * 16 + l15) * 64;
            bf16x8 bq0 = *(const bf16x8*)&Qs[rQ + c0s];
            bf16x8 bq1 = *(const bf16x8*)&Qs[rQ + c1s];
#pragma unroll
            for (int mi = 0; mi < 2; mi++) {
                f32x4 d = {0.f, 0.f, 0.f, 0.f};
                d = mfma16(ka[mi][0], bq0, d);
                d = mfma16(ka[mi][1], bq1, d);
#pragma unroll
                for (int r = 0; r < 4; r++)
                    acc[mi][r] += __expf(d[r] * 0.125f);
            }
        }
    }
#pragma unroll
    for (int mi = 0; mi < 2; mi++)
#pragma unroll
        for (int r = 0; r < 4; r++) {
            float v = acc[mi][r];
            v += __shfl_xor(v, 1); v += __shfl_xor(v, 2);
            v += __shfl_xor(v, 4); v += __shfl_xor(v, 8);
            if (l15 == 0)
                csum[(size_t)th * 65536 + (size_t)bh * 2048 + s_base + mi * 16 + q4 * 4 + r] = v;
        }
}

// ---------------- foldv: vt[bh][dh][s] = vrow[s][dh] / (c0[s]+c1[s]) ----------------
__global__ __launch_bounds__(256) void foldv(const ushort* __restrict__ vrow,
                                             const float* __restrict__ csum,
                                             ushort* __restrict__ vt) {
    __shared__ ushort T[64 * 72];
    int tid = threadIdx.x;
    int bh = blockIdx.x >> 5, sch = blockIdx.x & 31;
    int b = bh >> 4, h = bh & 15;
    int s0 = sch * 64;
    int sl = tid >> 3, dh8 = (tid & 7) * 8;
#pragma unroll
    for (int rep = 0; rep < 2; rep++) {
        int s = sl + rep * 32;
        size_t ci = (size_t)bh * 2048 + s0 + s;
        float n = 1.f / (csum[ci] + csum[65536 + ci]);
        const ushort* p = vrow + (size_t)(b * 2048 + s0 + s) * 1024 + h * 64 + dh8;
        ushort4 u0 = ((const ushort4*)p)[0];
        ushort4 u1 = ((const ushort4*)p)[1];
        ushort4 o0, o1;
        o0.x = f2bf(bf2f(u0.x) * n); o0.y = f2bf(bf2f(u0.y) * n);
        o0.z = f2bf(bf2f(u0.z) * n); o0.w = f2bf(bf2f(u0.w) * n);
        o1.x = f2bf(bf2f(u1.x) * n); o1.y = f2bf(bf2f(u1.y) * n);
        o1.z = f2bf(bf2f(u1.z) * n); o1.w = f2bf(bf2f(u1.w) * n);
        *(ushort4*)&T[s * 72 + dh8] = o0;
        *(ushort4*)&T[s * 72 + dh8 + 4] = o1;
    }
    __syncthreads();
    int dhl = tid >> 3, soff = (tid & 7) * 8;
#pragma unroll
    for (int rep = 0; rep < 2; rep++) {
        int d = dhl + rep * 32;
        ushort tmp[8];
#pragma unroll
        for (int j = 0; j < 8; j++) tmp[j] = T[(soff + j) * 72 + d];
        *(uint4*)(vt + ((size_t)bh * 64 + d) * 2048 + s0 + soff) = *(uint4*)tmp;
    }
}

// ---------------- attention pass B (s-split): partial O planes ----------------
// Block = (bh, tblk, shalf). Sweeps 1024 s; writes bf16 partial (no gelu).
__global__ __launch_bounds__(256) void attn_pv_split(const ushort* __restrict__ qb,
                                                     const ushort* __restrict__ kb,
                                                     const ushort* __restrict__ vt,
                                                     ushort* __restrict__ opart) {
    __shared__ ushort Ks[64 * 64];
    __shared__ ushort Vs[64 * 64];
    __shared__ ushort Ps[4][32 * 68];
    int tid = threadIdx.x, lane = tid & 63, w = tid >> 6;
    int id = blockIdx.x;
    int sh = id & 1, tblk = (id >> 1) & 15, bh = id >> 5;
    int b = bh >> 4, h = bh & 15;
    int q4 = lane >> 4, l15 = lane & 15;
    const ushort* qbase = qb + (size_t)(b * 2048) * 1024 + h * 64;
    const ushort* kbase = kb + (size_t)(b * 2048) * 1024 + h * 64;
    const ushort* vtb = vt + (size_t)bh * 64 * 2048;
    int t_base = tblk * 128 + w * 32;

    bf16x8 aq[2][2];
#pragma unroll
    for (int mi = 0; mi < 2; mi++) {
        const ushort* qp = qbase + (size_t)(t_base + mi * 16 + l15) * 1024 + q4 * 8;
        aq[mi][0] = *(const bf16x8*)(qp);
        aq[mi][1] = *(const bf16x8*)(qp + 32);
    }
    f32x4 oacc[2][4] = {};
    ushort* myP = Ps[w];

    int rl = lane >> 3;
    int cswz = (((lane & 7) ^ rl) << 3);
    int swf = l15 & 7;
    int c0s = (q4 ^ swf) << 3;
    int c1s = ((q4 + 4) ^ swf) << 3;
    int sEnd = sh * 1024 + 1024;
    for (int s0 = sh * 1024; s0 < sEnd; s0 += 64) {
        __syncthreads();
        gl2lds16(kbase + (size_t)(s0 + w * 16 + rl) * 1024 + cswz, Ks + (w * 16) * 64);
        gl2lds16(kbase + (size_t)(s0 + w * 16 + 8 + rl) * 1024 + cswz, Ks + (w * 16 + 8) * 64);
        gl2lds16(vtb + (size_t)(w * 16 + rl) * 2048 + s0 + cswz, Vs + (w * 16) * 64);
        gl2lds16(vtb + (size_t)(w * 16 + 8 + rl) * 2048 + s0 + cswz, Vs + (w * 16 + 8) * 64);
        __syncthreads();
        // S^T tiles: A = K rows (m=s), B = Q rows (n=t)
#pragma unroll
        for (int ssub = 0; ssub < 4; ssub++) {
            int rA = (ssub * 16 + l15) * 64;
            bf16x8 bk0 = *(const bf16x8*)&Ks[rA + c0s];
            bf16x8 bk1 = *(const bf16x8*)&Ks[rA + c1s];
#pragma unroll
            for (int mi = 0; mi < 2; mi++) {
                f32x4 d = {0.f, 0.f, 0.f, 0.f};
                d = mfma16(bk0, aq[mi][0], d);
                d = mfma16(bk1, aq[mi][1], d);
                float p0 = __expf(d[0] * 0.125f);
                float p1 = __expf(d[1] * 0.125f);
                float p2 = __expf(d[2] * 0.125f);
                float p3 = __expf(d[3] * 0.125f);
                uint2 uu;
                uu.x = pk2bf(p0, p1);
                uu.y = pk2bf(p2, p3);
                *(uint2*)&myP[(mi * 16 + l15) * 68 + ssub * 16 + q4 * 4] = uu;
            }
        }
        // PV: A = Pt (A-layout), B = Vs rows (dh-major, swizzled)
#pragma unroll
        for (int mi = 0; mi < 2; mi++) {
            bf16x8 ap0 = *(const bf16x8*)&myP[(mi * 16 + l15) * 68 + q4 * 8];
            bf16x8 ap1 = *(const bf16x8*)&myP[(mi * 16 + l15) * 68 + 32 + q4 * 8];
#pragma unroll
            for (int ni = 0; ni < 4; ni++) {
                int rV = (ni * 16 + l15) * 64;
                bf16x8 bv0 = *(const bf16x8*)&Vs[rV + c0s];
                bf16x8 bv1 = *(const bf16x8*)&Vs[rV + c1s];
                oacc[mi][ni] = mfma16(ap0, bv0, oacc[mi][ni]);
                oacc[mi][ni] = mfma16(ap1, bv1, oacc[mi][ni]);
            }
        }
    }
    ushort* op = opart + (size_t)sh * 4096 * 1024;
#pragma unroll
    for (int mi = 0; mi < 2; mi++)
#pragma unroll
        for (int ni = 0; ni < 4; ni++)
#pragma unroll
            for (int r = 0; r < 4; r++) {
                int t = t_base + mi * 16 + q4 * 4 + r;
                op[(size_t)(b * 2048 + t) * 1024 + h * 64 + ni * 16 + l15] =
                    f2bf(oacc[mi][ni][r]);
            }
}

// ---------------- attn_combine: post = gelu(p0+p1)/sqrt(S) ----------------
__global__ __launch_bounds__(256) void attn_combine(const ushort* __restrict__ opart,
                                                    ushort* __restrict__ post) {
    const size_t PLANE = (size_t)4096 * 1024;
    size_t base = ((size_t)blockIdx.x * 256 + threadIdx.x) * 8;
    ushort4 a0 = *(const ushort4*)(opart + base);
    ushort4 a1 = *(const ushort4*)(opart + base + 4);
    ushort4 b0 = *(const ushort4*)(opart + PLANE + base);
    ushort4 b1 = *(const ushort4*)(opart + PLANE + base + 4);
    const float sc = 0.022097086912079608f;  // 1/sqrt(2048)
    ushort4 o0, o1;
    o0.x = f2bf(gelu_fast(bf2f(a0.x) + bf2f(b0.x)) * sc);
    o0.y = f2bf(gelu_fast(bf2f(a0.y) + bf2f(b0.y)) * sc);
    o0.z = f2bf(gelu_fast(bf2f(a0.z) + bf2f(b0.z)) * sc);
    o0.w = f2bf(gelu_fast(bf2f(a0.w) + bf2f(b0.w)) * sc);
    o1.x = f2bf(gelu_fast(bf2f(a1.x) + bf2f(b1.x)) * sc);
    o1.y = f2bf(gelu_fast(bf2f(a1.y) + bf2f(b1.y)) * sc);
    o1.z = f2bf(gelu_fast(bf2f(a1.z) + bf2f(b1.z)) * sc);
    o1.w = f2bf(gelu_fast(bf2f(a1.w) + bf2f(b1.w)) * sc);
    *(ushort4*)(post + base) = o0;
    *(ushort4*)(post + base + 4) = o1;
}

// ---------------- LayerNorm with fused 4-plane bf16 split-K combine ----------------
__global__ __launch_bounds__(256) void ln_comb4(const ushort* __restrict__ parts,
                                                const float* __restrict__ bias,
                                                const float* __restrict__ res,
                                                const float* __restrict__ gw,
                                                const float* __restrict__ bw,
                                                ushort* __restrict__ outb,
                                                float* __restrict__ outf) {
    const size_t PLANE = (size_t)4096 * 1024;
    int row = blockIdx.x, tid = threadIdx.x;
    int lane = tid & 63, wid = tid >> 6;
    size_t off = (size_t)row * 1024 + tid * 4;
    float4 r = *(const float4*)(res + off);
    float4 bb = *(const float4*)(bias + tid * 4);
    float4 v;
    v.x = r.x + bb.x; v.y = r.y + bb.y; v.z = r.z + bb.z; v.w = r.w + bb.w;
#pragma unroll
    for (int p = 0; p < 4; p++) {
        ushort4 u = *(const ushort4*)(parts + p * PLANE + off);
        v.x += bf2f(u.x); v.y += bf2f(u.y); v.z += bf2f(u.z); v.w += bf2f(u.w);
    }
    float s = v.x + v.y + v.z + v.w;
    float ss = v.x * v.x + v.y * v.y + v.z * v.z + v.w * v.w;
    for (int m = 1; m < 64; m <<= 1) { s += __shfl_xor(s, m); ss += __shfl_xor(ss, m); }
    __shared__ float red[8];
    if (lane == 0) { red[wid] = s; red[wid + 4] = ss; }
    __syncthreads();
    s = red[0] + red[1] + red[2] + red[3];
    ss = red[4] + red[5] + red[6] + red[7];
    float mu = s * (1.f / 1024.f);
    float var = ss * (1.f / 1024.f) - mu * mu;
    float inv = rsqrtf(var + 1e-5f);
    float4 gv = *(const float4*)(gw + tid * 4);
    float4 bv = *(const float4*)(bw + tid * 4);
    float o0 = (v.x - mu) * inv * gv.x + bv.x;
    float o1 = (v.y - mu) * inv * gv.y + bv.y;
    float o2 = (v.z - mu) * inv * gv.z + bv.z;
    float o3 = (v.w - mu) * inv * gv.w + bv.w;
    if (outf) {
        float4 o; o.x = o0; o.y = o1; o.z = o2; o.w = o3;
        *(float4*)(outf + off) = o;
    }
    if (outb) {
        ushort4 o; o.x = f2bf(o0); o.y = f2bf(o1); o.z = f2bf(o2); o.w = f2bf(o3);
        *(ushort4*)(outb + off) = o;
    }
}

extern "C" void kernel_launch(void* const* d_in, const int* in_sizes, int n_in,
                              void* d_out, int out_size, void* d_ws, size_t ws_size,
                              hipStream_t stream) {
    const float* src  = (const float*)d_in[0];
    const float* w_in = (const float*)d_in[1];
    const float* b_in = (const float*)d_in[2];
    const float* w_o  = (const float*)d_in[3];
    const float* b_o  = (const float*)d_in[4];
    const float* w1   = (const float*)d_in[5];
    const float* b1   = (const float*)d_in[6];
    const float* w2   = (const float*)d_in[7];
    const float* b2   = (const float*)d_in[8];
    const float* g1   = (const float*)d_in[9];
    const float* be1  = (const float*)d_in[10];
    const float* g2   = (const float*)d_in[11];
    const float* be2  = (const float*)d_in[12];
    float* out = (float*)d_out;

    const size_t M = 4096;
    char* wsp = (char*)d_ws;
    size_t off = 0;
    auto alloc = [&](size_t bytes) -> void* {
        void* p = wsp + off;
        off = (off + bytes + 255) & ~(size_t)255;
        return p;
    };
    // NOTE: first five bf16 buffers must stay contiguous (cvt_all writes them flat).
    ushort* src_bf  = (ushort*)alloc(M * 1024 * 2);
    ushort* win_bf  = (ushort*)alloc(3072 * 1024 * 2);
    ushort* wout_bf = (ushort*)alloc(1024 * 1024 * 2);
    ushort* w1_bf   = (ushort*)alloc(4096 * 1024 * 2);
    ushort* w2_bf   = (ushort*)alloc((size_t)1024 * 4096 * 2);
    ushort* q_bf    = (ushort*)alloc(M * 1024 * 2);
    ushort* k_bf    = (ushort*)alloc(M * 1024 * 2);
    ushort* vt_bf   = (ushort*)alloc(M * 1024 * 2);
    ushort* post_bf = (ushort*)alloc(M * 1024 * 2);
    ushort* part    = (ushort*)alloc(4 * M * 1024 * 2);  // 4 bf16 split-K planes
    float*  csum    = (float*)alloc(2 * 32 * 2048 * 4);  // t-split colsum partials
    ushort* x_bf    = (ushort*)alloc(M * 1024 * 2);
    float*  x_f32   = (float*)alloc(M * 1024 * 4);
    ushort* h1_bf   = (ushort*)alloc(M * 4096 * 2);
    // aliases into part (stream-ordered lifetimes):
    ushort* v_row   = part;                    // plane 0: V row-major (dead after foldv)
    ushort* opart   = part + M * 1024;         // planes 1-2: attn_pv partial O

    // 1) convert all fp32 inputs to bf16
    cvt_all<<<16384, 256, 0, stream>>>((const float4*)src, (const float4*)w_in,
                                       (const float4*)w_o, (const float4*)w1,
                                       (const float4*)w2, (ushort4*)src_bf);

    // 2) QKV projection
    gemm_bt<<<dim3(24, 32, 1), 256, 0, stream>>>(src_bf, win_bf, b_in, 4096, 3072, 1024, 1024, 0, 2,
                                                 q_bf, k_bf, v_row);

    // 3) attention: colsum (t-split) -> foldv -> PV (s-split) -> combine
    attn_colsum_part<<<1024, 256, 0, stream>>>(q_bf, k_bf, csum);
    foldv<<<1024, 256, 0, stream>>>(v_row, csum, vt_bf);
    attn_pv_split<<<1024, 256, 0, stream>>>(q_bf, k_bf, vt_bf, opart);
    attn_combine<<<2048, 256, 0, stream>>>(opart, post_bf);

    // 4) out-proj (split-K=4, bf16 partials) -> LN1 combine(+b_o, +src)
    gemm_bt<<<dim3(8, 32, 4), 256, 0, stream>>>(post_bf, wout_bf, b_o, 4096, 1024, 1024, 256, 3, 1,
                                                part, nullptr, nullptr);
    ln_comb4<<<4096, 256, 0, stream>>>(part, b_o, src, g1, be1, x_bf, x_f32);

    // 5) FF: lin1+gelu ; lin2 (split-K=4) -> LN2 combine(+b2, +x)
    gemm_bt<<<dim3(32, 32, 1), 256, 0, stream>>>(x_bf, w1_bf, b1, 4096, 4096, 1024, 1024, 2, 2,
                                                 h1_bf, nullptr, nullptr);
    gemm_bt<<<dim3(8, 32, 4), 256, 0, stream>>>(h1_bf, w2_bf, b2, 4096, 1024, 4096, 1024, 3, 1,
                                                part, nullptr, nullptr);
    ln_comb4<<<4096, 256, 0, stream>>>(part, b2, x_f32, g2, be2, nullptr, out);
}

// Round 9
// 441.686 us; speedup vs baseline: 1.0918x; 1.0545x over previous
//
#include <hip/hip_runtime.h>
#include <hip/hip_bf16.h>
#include <math.h>

// Round 8: (a) gemm_bt operand-swapped MFMA -> C-tile exits with 4 consecutive
// cols per lane: epilogue = pk2bf pairs + 8B stores (16 instead of 64 stores,
// half the cvts). (b) attention blocks pinned to XCD by head (id%8 = head%8)
// so each XCD's L2 keeps one head-set of Q/K/V resident.

using bf16x8 = __attribute__((ext_vector_type(8))) short;
using f32x4  = __attribute__((ext_vector_type(4))) float;

__device__ inline f32x4 mfma16(bf16x8 a, bf16x8 b, f32x4 c) {
    return __builtin_amdgcn_mfma_f32_16x16x32_bf16(a, b, c, 0, 0, 0);
}

__device__ inline ushort f2bf(float f) {
    union { float f; unsigned u; } x; x.f = f;
    unsigned r = x.u + 0x7fffu + ((x.u >> 16) & 1u);
    return (ushort)(r >> 16);
}

__device__ inline float bf2f(ushort u) {
    union { unsigned u; float f; } x; x.u = ((unsigned)u) << 16; return x.f;
}

// pack two floats -> two bf16 (v_cvt_pk_bf16_f32 on gfx950)
__device__ inline unsigned pk2bf(float a, float b) {
    __hip_bfloat162 h = __float22bfloat162_rn(float2{a, b});
    union { __hip_bfloat162 h; unsigned u; } x; x.h = h;
    return x.u;
}

// tanh-form gelu: v * sigmoid(1.59577v + 0.071355v^3); max |err| vs erf ~3e-3
__device__ inline float gelu_fast(float v) {
    float u = v * (1.5957691216f + 0.0713548162f * v * v);
    float e = __expf(u);
    return v * (e / (e + 1.0f));
}

// async 16B global -> LDS (wave-uniform LDS base + lane*16)
__device__ __forceinline__ void gl2lds16(const ushort* g, ushort* l) {
    __builtin_amdgcn_global_load_lds(
        (const __attribute__((address_space(1))) unsigned int*)g,
        (__attribute__((address_space(3))) unsigned int*)l,
        16, 0, 0);
}

// ---------------- merged fp32 -> bf16 convert ----------------
__global__ __launch_bounds__(256) void cvt_all(const float4* __restrict__ s0,
                                               const float4* __restrict__ s1,
                                               const float4* __restrict__ s2,
                                               const float4* __restrict__ s3,
                                               const float4* __restrict__ s4,
                                               ushort4* __restrict__ out) {
    int i = blockIdx.x * 256 + threadIdx.x;
    const float4* p;
    int off;
    if (i < 1048576)      { p = s0; off = i; }
    else if (i < 1835008) { p = s1; off = i - 1048576; }
    else if (i < 2097152) { p = s2; off = i - 1835008; }
    else if (i < 3145728) { p = s3; off = i - 2097152; }
    else                  { p = s4; off = i - 3145728; }
    float4 v = p[off];
    ushort4 o;
    o.x = f2bf(v.x); o.y = f2bf(v.y); o.z = f2bf(v.z); o.w = f2bf(v.w);
    out[i] = o;
}

// ---------------- GEMM: out[M,N] = A[M,K] @ Bw[N,K]^T (+ bias) ----------------
// Operand-swapped MFMA: lane holds (row = mi*16+l15, cols = ni*16+q4*4+0..3).
// mode 0: QKV epilogue -> ob0 (Q), ob1 (K), ob2 (V row-major); +bias
// mode 2: bf16 out = gelu(acc + bias)
// mode 3: bf16 partial: ob0[z*M*N + idx] = acc (bias added in LN combine)
__global__ __launch_bounds__(256) void gemm_bt(
    const ushort* __restrict__ A, const ushort* __restrict__ Bw,
    const float* __restrict__ bias, int M, int N, int K, int kLen, int mode, int gx,
    ushort* __restrict__ ob0, ushort* __restrict__ ob1, ushort* __restrict__ ob2) {
    __shared__ ushort As[2][128 * 32];
    __shared__ ushort Bs[2][128 * 32];
    int tid = threadIdx.x, lane = tid & 63, w = tid >> 6;
    int wm = w >> 1, wn = w & 1;

    int Nx = gridDim.x, Ny = gridDim.y;
    int bx = blockIdx.x, by = blockIdx.y;
    int gy = 8 / gx;
    if ((Nx % gx) == 0 && (Ny % gy) == 0 && ((Nx * Ny) & 7) == 0) {
        int Sx = Nx / gx, Sy = Ny / gy;
        int i = bx + Nx * by;
        int c = i & 7, j = i >> 3;
        int cx = c % gx, cy = c / gx;
        bx = cx * Sx + j % Sx;
        by = cy * Sy + (j / Sx) % Sy;
    }
    int bm = by * 128, bn = bx * 128;
    int kz = blockIdx.z;
    int q4 = lane >> 4, l15 = lane & 15;
    f32x4 acc[4][4] = {};

    int srow = w * 16 + (lane >> 2);
    int scg = lane & 3;
    const ushort* Ab = A + (size_t)bm * K + (size_t)kz * kLen;
    const ushort* Bb = Bw + (size_t)bn * K + (size_t)kz * kLen;
    const ushort* gA0 = Ab + (size_t)srow * K + scg * 8;
    const ushort* gA1 = Ab + (size_t)(64 + srow) * K + scg * 8;
    const ushort* gB0 = Bb + (size_t)srow * K + scg * 8;
    const ushort* gB1 = Bb + (size_t)(64 + srow) * K + scg * 8;
    ushort* lA00 = As[0] + w * 512;
    ushort* lA10 = As[0] + 2048 + w * 512;
    ushort* lB00 = Bs[0] + w * 512;
    ushort* lB10 = Bs[0] + 2048 + w * 512;
    ushort* lA01 = As[1] + w * 512;
    ushort* lA11 = As[1] + 2048 + w * 512;
    ushort* lB01 = Bs[1] + w * 512;
    ushort* lB11 = Bs[1] + 2048 + w * 512;

    const ushort* aB[2] = { &As[0][(wm * 64 + l15) * 32 + q4 * 8],
                            &As[1][(wm * 64 + l15) * 32 + q4 * 8] };
    const ushort* bB[2] = { &Bs[0][(wn * 64 + l15) * 32 + q4 * 8],
                            &Bs[1][(wn * 64 + l15) * 32 + q4 * 8] };

    for (int k0 = 0; k0 < kLen; k0 += 64) {
        __syncthreads();
        gl2lds16(gA0 + k0, lA00);
        gl2lds16(gA1 + k0, lA10);
        gl2lds16(gB0 + k0, lB00);
        gl2lds16(gB1 + k0, lB10);
        gl2lds16(gA0 + k0 + 32, lA01);
        gl2lds16(gA1 + k0 + 32, lA11);
        gl2lds16(gB0 + k0 + 32, lB01);
        gl2lds16(gB1 + k0 + 32, lB11);
        __syncthreads();
#pragma unroll
        for (int u = 0; u < 2; u++) {
            bf16x8 af[4], bfr[4];
#pragma unroll
            for (int mi = 0; mi < 4; mi++)
                af[mi] = *(const bf16x8*)(aB[u] + mi * 512);
#pragma unroll
            for (int ni = 0; ni < 4; ni++)
                bfr[ni] = *(const bf16x8*)(bB[u] + ni * 512);
            // swapped: D[n][m]; lane -> row=l15(+mi*16), cols=q4*4+r(+ni*16)
#pragma unroll
            for (int mi = 0; mi < 4; mi++)
#pragma unroll
                for (int ni = 0; ni < 4; ni++)
                    acc[mi][ni] = mfma16(bfr[ni], af[mi], acc[mi][ni]);
        }
    }

    int r0 = bm + wm * 64, c0 = bn + wn * 64;
#pragma unroll
    for (int mi = 0; mi < 4; mi++) {
        int rowg = r0 + mi * 16 + l15;
#pragma unroll
        for (int ni = 0; ni < 4; ni++) {
            int colb = c0 + ni * 16 + q4 * 4;       // 4 consecutive cols
            float v0 = acc[mi][ni][0], v1 = acc[mi][ni][1];
            float v2 = acc[mi][ni][2], v3 = acc[mi][ni][3];
            if (mode != 3) {
                float4 bb = *(const float4*)(bias + colb);
                v0 += bb.x; v1 += bb.y; v2 += bb.z; v3 += bb.w;
            }
            if (mode == 2) {
                v0 = gelu_fast(v0); v1 = gelu_fast(v1);
                v2 = gelu_fast(v2); v3 = gelu_fast(v3);
            }
            uint2 uu;
            uu.x = pk2bf(v0, v1);
            uu.y = pk2bf(v2, v3);
            if (mode == 0) {
                if (colb < 1024) {
                    *(uint2*)&ob0[(size_t)rowg * 1024 + colb] = uu;
                } else if (colb < 2048) {
                    *(uint2*)&ob1[(size_t)rowg * 1024 + (colb - 1024)] = uu;
                } else {
                    *(uint2*)&ob2[(size_t)rowg * 1024 + (colb - 2048)] = uu;
                }
            } else if (mode == 2) {
                *(uint2*)&ob0[(size_t)rowg * N + colb] = uu;
            } else {
                *(uint2*)&ob0[(size_t)kz * M * N + (size_t)rowg * N + colb] = uu;
            }
        }
    }
}

// ---------------- attention pass A (t-split): partial colsum[s] ----------------
// Block swizzle: id%8 = bh%8 -> one head-set pinned per XCD.
__global__ __launch_bounds__(256) void attn_colsum_part(const ushort* __restrict__ qb,
                                                        const ushort* __restrict__ kb,
                                                        float* __restrict__ csum) {
    __shared__ ushort Qs[64 * 64];
    int tid = threadIdx.x, lane = tid & 63, w = tid >> 6;
    int id = blockIdx.x;
    int xcd = id & 7, g = id >> 3;
    int sub = g & 31, bh = (g >> 5) * 8 + xcd;
    int th = sub & 1, sblk = sub >> 1;
    int b = bh >> 4, h = bh & 15;
    int q4 = lane >> 4, l15 = lane & 15;
    const ushort* qbase = qb + (size_t)(b * 2048) * 1024 + h * 64;
    const ushort* kbase = kb + (size_t)(b * 2048) * 1024 + h * 64;
    int s_base = sblk * 128 + w * 32;

    bf16x8 ka[2][2];
#pragma unroll
    for (int mi = 0; mi < 2; mi++) {
        const ushort* kp = kbase + (size_t)(s_base + mi * 16 + l15) * 1024 + q4 * 8;
        ka[mi][0] = *(const bf16x8*)(kp);
        ka[mi][1] = *(const bf16x8*)(kp + 32);
    }
    float acc[2][4] = {};

    int rl = lane >> 3;
    int cswz = (((lane & 7) ^ rl) << 3);
    int swf = l15 & 7;
    int c0s = (q4 ^ swf) << 3;
    int c1s = ((q4 + 4) ^ swf) << 3;
    int tEnd = th * 1024 + 1024;
    for (int t0 = th * 1024; t0 < tEnd; t0 += 64) {
        __syncthreads();
        gl2lds16(qbase + (size_t)(t0 + w * 16 + rl) * 1024 + cswz, Qs + (w * 16) * 64);
        gl2lds16(qbase + (size_t)(t0 + w * 16 + 8 + rl) * 1024 + cswz, Qs + (w * 16 + 8) * 64);
        __syncthreads();
#pragma unroll
        for (int tsub = 0; tsub < 4; tsub++) {
            int rQ = (tsub * 16 + l15) * 64;
            bf16x8 bq0 = *(const bf16x8*)&Qs[rQ + c0s];
            bf16x8 bq1 = *(const bf16x8*)&Qs[rQ + c1s];
#pragma unroll
            for (int mi = 0; mi < 2; mi++) {
                f32x4 d = {0.f, 0.f, 0.f, 0.f};
                d = mfma16(ka[mi][0], bq0, d);
                d = mfma16(ka[mi][1], bq1, d);
#pragma unroll
                for (int r = 0; r < 4; r++)
                    acc[mi][r] += __expf(d[r] * 0.125f);
            }
        }
    }
#pragma unroll
    for (int mi = 0; mi < 2; mi++)
#pragma unroll
        for (int r = 0; r < 4; r++) {
            float v = acc[mi][r];
            v += __shfl_xor(v, 1); v += __shfl_xor(v, 2);
            v += __shfl_xor(v, 4); v += __shfl_xor(v, 8);
            if (l15 == 0)
                csum[(size_t)th * 65536 + (size_t)bh * 2048 + s_base + mi * 16 + q4 * 4 + r] = v;
        }
}

// ---------------- foldv: vt[bh][dh][s] = vrow[s][dh] / (c0[s]+c1[s]) ----------------
__global__ __launch_bounds__(256) void foldv(const ushort* __restrict__ vrow,
                                             const float* __restrict__ csum,
                                             ushort* __restrict__ vt) {
    __shared__ ushort T[64 * 72];
    int tid = threadIdx.x;
    int id = blockIdx.x;
    int xcd = id & 7, g = id >> 3;
    int sch = g & 31, bh = (g >> 5) * 8 + xcd;
    int b = bh >> 4, h = bh & 15;
    int s0 = sch * 64;
    int sl = tid >> 3, dh8 = (tid & 7) * 8;
#pragma unroll
    for (int rep = 0; rep < 2; rep++) {
        int s = sl + rep * 32;
        size_t ci = (size_t)bh * 2048 + s0 + s;
        float n = 1.f / (csum[ci] + csum[65536 + ci]);
        const ushort* p = vrow + (size_t)(b * 2048 + s0 + s) * 1024 + h * 64 + dh8;
        ushort4 u0 = ((const ushort4*)p)[0];
        ushort4 u1 = ((const ushort4*)p)[1];
        ushort4 o0, o1;
        o0.x = f2bf(bf2f(u0.x) * n); o0.y = f2bf(bf2f(u0.y) * n);
        o0.z = f2bf(bf2f(u0.z) * n); o0.w = f2bf(bf2f(u0.w) * n);
        o1.x = f2bf(bf2f(u1.x) * n); o1.y = f2bf(bf2f(u1.y) * n);
        o1.z = f2bf(bf2f(u1.z) * n); o1.w = f2bf(bf2f(u1.w) * n);
        *(ushort4*)&T[s * 72 + dh8] = o0;
        *(ushort4*)&T[s * 72 + dh8 + 4] = o1;
    }
    __syncthreads();
    int dhl = tid >> 3, soff = (tid & 7) * 8;
#pragma unroll
    for (int rep = 0; rep < 2; rep++) {
        int d = dhl + rep * 32;
        ushort tmp[8];
#pragma unroll
        for (int j = 0; j < 8; j++) tmp[j] = T[(soff + j) * 72 + d];
        *(uint4*)(vt + ((size_t)bh * 64 + d) * 2048 + s0 + soff) = *(uint4*)tmp;
    }
}

// ---------------- attention pass B (s-split): partial O planes ----------------
__global__ __launch_bounds__(256) void attn_pv_split(const ushort* __restrict__ qb,
                                                     const ushort* __restrict__ kb,
                                                     const ushort* __restrict__ vt,
                                                     ushort* __restrict__ opart) {
    __shared__ ushort Ks[64 * 64];
    __shared__ ushort Vs[64 * 64];
    __shared__ ushort Ps[4][32 * 68];
    int tid = threadIdx.x, lane = tid & 63, w = tid >> 6;
    int id = blockIdx.x;
    int xcd = id & 7, g = id >> 3;
    int sub = g & 31, bh = (g >> 5) * 8 + xcd;
    int sh = sub & 1, tblk = sub >> 1;
    int b = bh >> 4, h = bh & 15;
    int q4 = lane >> 4, l15 = lane & 15;
    const ushort* qbase = qb + (size_t)(b * 2048) * 1024 + h * 64;
    const ushort* kbase = kb + (size_t)(b * 2048) * 1024 + h * 64;
    const ushort* vtb = vt + (size_t)bh * 64 * 2048;
    int t_base = tblk * 128 + w * 32;

    bf16x8 aq[2][2];
#pragma unroll
    for (int mi = 0; mi < 2; mi++) {
        const ushort* qp = qbase + (size_t)(t_base + mi * 16 + l15) * 1024 + q4 * 8;
        aq[mi][0] = *(const bf16x8*)(qp);
        aq[mi][1] = *(const bf16x8*)(qp + 32);
    }
    f32x4 oacc[2][4] = {};
    ushort* myP = Ps[w];

    int rl = lane >> 3;
    int cswz = (((lane & 7) ^ rl) << 3);
    int swf = l15 & 7;
    int c0s = (q4 ^ swf) << 3;
    int c1s = ((q4 + 4) ^ swf) << 3;
    int sEnd = sh * 1024 + 1024;
    for (int s0 = sh * 1024; s0 < sEnd; s0 += 64) {
        __syncthreads();
        gl2lds16(kbase + (size_t)(s0 + w * 16 + rl) * 1024 + cswz, Ks + (w * 16) * 64);
        gl2lds16(kbase + (size_t)(s0 + w * 16 + 8 + rl) * 1024 + cswz, Ks + (w * 16 + 8) * 64);
        gl2lds16(vtb + (size_t)(w * 16 + rl) * 2048 + s0 + cswz, Vs + (w * 16) * 64);
        gl2lds16(vtb + (size_t)(w * 16 + 8 + rl) * 2048 + s0 + cswz, Vs + (w * 16 + 8) * 64);
        __syncthreads();
        // S^T tiles: A = K rows (m=s), B = Q rows (n=t)
#pragma unroll
        for (int ssub = 0; ssub < 4; ssub++) {
            int rA = (ssub * 16 + l15) * 64;
            bf16x8 bk0 = *(const bf16x8*)&Ks[rA + c0s];
            bf16x8 bk1 = *(const bf16x8*)&Ks[rA + c1s];
#pragma unroll
            for (int mi = 0; mi < 2; mi++) {
                f32x4 d = {0.f, 0.f, 0.f, 0.f};
                d = mfma16(bk0, aq[mi][0], d);
                d = mfma16(bk1, aq[mi][1], d);
                float p0 = __expf(d[0] * 0.125f);
                float p1 = __expf(d[1] * 0.125f);
                float p2 = __expf(d[2] * 0.125f);
                float p3 = __expf(d[3] * 0.125f);
                uint2 uu;
                uu.x = pk2bf(p0, p1);
                uu.y = pk2bf(p2, p3);
                *(uint2*)&myP[(mi * 16 + l15) * 68 + ssub * 16 + q4 * 4] = uu;
            }
        }
        // PV: A = Pt (A-layout), B = Vs rows (dh-major, swizzled)
#pragma unroll
        for (int mi = 0; mi < 2; mi++) {
            bf16x8 ap0 = *(const bf16x8*)&myP[(mi * 16 + l15) * 68 + q4 * 8];
            bf16x8 ap1 = *(const bf16x8*)&myP[(mi * 16 + l15) * 68 + 32 + q4 * 8];
#pragma unroll
            for (int ni = 0; ni < 4; ni++) {
                int rV = (ni * 16 + l15) * 64;
                bf16x8 bv0 = *(const bf16x8*)&Vs[rV + c0s];
                bf16x8 bv1 = *(const bf16x8*)&Vs[rV + c1s];
                oacc[mi][ni] = mfma16(ap0, bv0, oacc[mi][ni]);
                oacc[mi][ni] = mfma16(ap1, bv1, oacc[mi][ni]);
            }
        }
    }
    ushort* op = opart + (size_t)sh * 4096 * 1024;
#pragma unroll
    for (int mi = 0; mi < 2; mi++)
#pragma unroll
        for (int ni = 0; ni < 4; ni++)
#pragma unroll
            for (int r = 0; r < 4; r++) {
                int t = t_base + mi * 16 + q4 * 4 + r;
                op[(size_t)(b * 2048 + t) * 1024 + h * 64 + ni * 16 + l15] =
                    f2bf(oacc[mi][ni][r]);
            }
}

// ---------------- attn_combine: post = gelu(p0+p1)/sqrt(S) ----------------
__global__ __launch_bounds__(256) void attn_combine(const ushort* __restrict__ opart,
                                                    ushort* __restrict__ post) {
    const size_t PLANE = (size_t)4096 * 1024;
    size_t base = ((size_t)blockIdx.x * 256 + threadIdx.x) * 8;
    ushort4 a0 = *(const ushort4*)(opart + base);
    ushort4 a1 = *(const ushort4*)(opart + base + 4);
    ushort4 b0 = *(const ushort4*)(opart + PLANE + base);
    ushort4 b1 = *(const ushort4*)(opart + PLANE + base + 4);
    const float sc = 0.022097086912079608f;  // 1/sqrt(2048)
    ushort4 o0, o1;
    o0.x = f2bf(gelu_fast(bf2f(a0.x) + bf2f(b0.x)) * sc);
    o0.y = f2bf(gelu_fast(bf2f(a0.y) + bf2f(b0.y)) * sc);
    o0.z = f2bf(gelu_fast(bf2f(a0.z) + bf2f(b0.z)) * sc);
    o0.w = f2bf(gelu_fast(bf2f(a0.w) + bf2f(b0.w)) * sc);
    o1.x = f2bf(gelu_fast(bf2f(a1.x) + bf2f(b1.x)) * sc);
    o1.y = f2bf(gelu_fast(bf2f(a1.y) + bf2f(b1.y)) * sc);
    o1.z = f2bf(gelu_fast(bf2f(a1.z) + bf2f(b1.z)) * sc);
    o1.w = f2bf(gelu_fast(bf2f(a1.w) + bf2f(b1.w)) * sc);
    *(ushort4*)(post + base) = o0;
    *(ushort4*)(post + base + 4) = o1;
}

// ---------------- LayerNorm with fused 4-plane bf16 split-K combine ----------------
__global__ __launch_bounds__(256) void ln_comb4(const ushort* __restrict__ parts,
                                                const float* __restrict__ bias,
                                                const float* __restrict__ res,
                                                const float* __restrict__ gw,
                                                const float* __restrict__ bw,
                                                ushort* __restrict__ outb,
                                                float* __restrict__ outf) {
    const size_t PLANE = (size_t)4096 * 1024;
    int row = blockIdx.x, tid = threadIdx.x;
    int lane = tid & 63, wid = tid >> 6;
    size_t off = (size_t)row * 1024 + tid * 4;
    float4 r = *(const float4*)(res + off);
    float4 bb = *(const float4*)(bias + tid * 4);
    float4 v;
    v.x = r.x + bb.x; v.y = r.y + bb.y; v.z = r.z + bb.z; v.w = r.w + bb.w;
#pragma unroll
    for (int p = 0; p < 4; p++) {
        ushort4 u = *(const ushort4*)(parts + p * PLANE + off);
        v.x += bf2f(u.x); v.y += bf2f(u.y); v.z += bf2f(u.z); v.w += bf2f(u.w);
    }
    float s = v.x + v.y + v.z + v.w;
    float ss = v.x * v.x + v.y * v.y + v.z * v.z + v.w * v.w;
    for (int m = 1; m < 64; m <<= 1) { s += __shfl_xor(s, m); ss += __shfl_xor(ss, m); }
    __shared__ float red[8];
    if (lane == 0) { red[wid] = s; red[wid + 4] = ss; }
    __syncthreads();
    s = red[0] + red[1] + red[2] + red[3];
    ss = red[4] + red[5] + red[6] + red[7];
    float mu = s * (1.f / 1024.f);
    float var = ss * (1.f / 1024.f) - mu * mu;
    float inv = rsqrtf(var + 1e-5f);
    float4 gv = *(const float4*)(gw + tid * 4);
    float4 bv = *(const float4*)(bw + tid * 4);
    float o0 = (v.x - mu) * inv * gv.x + bv.x;
    float o1 = (v.y - mu) * inv * gv.y + bv.y;
    float o2 = (v.z - mu) * inv * gv.z + bv.z;
    float o3 = (v.w - mu) * inv * gv.w + bv.w;
    if (outf) {
        float4 o; o.x = o0; o.y = o1; o.z = o2; o.w = o3;
        *(float4*)(outf + off) = o;
    }
    if (outb) {
        ushort4 o; o.x = f2bf(o0); o.y = f2bf(o1); o.z = f2bf(o2); o.w = f2bf(o3);
        *(ushort4*)(outb + off) = o;
    }
}

extern "C" void kernel_launch(void* const* d_in, const int* in_sizes, int n_in,
                              void* d_out, int out_size, void* d_ws, size_t ws_size,
                              hipStream_t stream) {
    const float* src  = (const float*)d_in[0];
    const float* w_in = (const float*)d_in[1];
    const float* b_in = (const float*)d_in[2];
    const float* w_o  = (const float*)d_in[3];
    const float* b_o  = (const float*)d_in[4];
    const float* w1   = (const float*)d_in[5];
    const float* b1   = (const float*)d_in[6];
    const float* w2   = (const float*)d_in[7];
    const float* b2   = (const float*)d_in[8];
    const float* g1   = (const float*)d_in[9];
    const float* be1  = (const float*)d_in[10];
    const float* g2   = (const float*)d_in[11];
    const float* be2  = (const float*)d_in[12];
    float* out = (float*)d_out;

    const size_t M = 4096;
    char* wsp = (char*)d_ws;
    size_t off = 0;
    auto alloc = [&](size_t bytes) -> void* {
        void* p = wsp + off;
        off = (off + bytes + 255) & ~(size_t)255;
        return p;
    };
    // NOTE: first five bf16 buffers must stay contiguous (cvt_all writes them flat).
    ushort* src_bf  = (ushort*)alloc(M * 1024 * 2);
    ushort* win_bf  = (ushort*)alloc(3072 * 1024 * 2);
    ushort* wout_bf = (ushort*)alloc(1024 * 1024 * 2);
    ushort* w1_bf   = (ushort*)alloc(4096 * 1024 * 2);
    ushort* w2_bf   = (ushort*)alloc((size_t)1024 * 4096 * 2);
    ushort* q_bf    = (ushort*)alloc(M * 1024 * 2);
    ushort* k_bf    = (ushort*)alloc(M * 1024 * 2);
    ushort* vt_bf   = (ushort*)alloc(M * 1024 * 2);
    ushort* post_bf = (ushort*)alloc(M * 1024 * 2);
    ushort* part    = (ushort*)alloc(4 * M * 1024 * 2);  // 4 bf16 split-K planes
    float*  csum    = (float*)alloc(2 * 32 * 2048 * 4);  // t-split colsum partials
    ushort* x_bf    = (ushort*)alloc(M * 1024 * 2);
    float*  x_f32   = (float*)alloc(M * 1024 * 4);
    ushort* h1_bf   = (ushort*)alloc(M * 4096 * 2);
    // aliases into part (stream-ordered lifetimes):
    ushort* v_row   = part;                    // plane 0: V row-major (dead after foldv)
    ushort* opart   = part + M * 1024;         // planes 1-2: attn_pv partial O

    // 1) convert all fp32 inputs to bf16
    cvt_all<<<16384, 256, 0, stream>>>((const float4*)src, (const float4*)w_in,
                                       (const float4*)w_o, (const float4*)w1,
                                       (const float4*)w2, (ushort4*)src_bf);

    // 2) QKV projection
    gemm_bt<<<dim3(24, 32, 1), 256, 0, stream>>>(src_bf, win_bf, b_in, 4096, 3072, 1024, 1024, 0, 2,
                                                 q_bf, k_bf, v_row);

    // 3) attention: colsum (t-split) -> foldv -> PV (s-split) -> combine
    attn_colsum_part<<<1024, 256, 0, stream>>>(q_bf, k_bf, csum);
    foldv<<<1024, 256, 0, stream>>>(v_row, csum, vt_bf);
    attn_pv_split<<<1024, 256, 0, stream>>>(q_bf, k_bf, vt_bf, opart);
    attn_combine<<<2048, 256, 0, stream>>>(opart, post_bf);

    // 4) out-proj (split-K=4, bf16 partials) -> LN1 combine(+b_o, +src)
    gemm_bt<<<dim3(8, 32, 4), 256, 0, stream>>>(post_bf, wout_bf, b_o, 4096, 1024, 1024, 256, 3, 1,
                                                part, nullptr, nullptr);
    ln_comb4<<<4096, 256, 0, stream>>>(part, b_o, src, g1, be1, x_bf, x_f32);

    // 5) FF: lin1+gelu ; lin2 (split-K=4) -> LN2 combine(+b2, +x)
    gemm_bt<<<dim3(32, 32, 1), 256, 0, stream>>>(x_bf, w1_bf, b1, 4096, 4096, 1024, 1024, 2, 2,
                                                 h1_bf, nullptr, nullptr);
    gemm_bt<<<dim3(8, 32, 4), 256, 0, stream>>>(h1_bf, w2_bf, b2, 4096, 1024, 4096, 1024, 3, 1,
                                                part, nullptr, nullptr);
    ln_comb4<<<4096, 256, 0, stream>>>(part, b2, x_f32, g2, be2, nullptr, out);
}